// Round 5
// baseline (590.494 us; speedup 1.0000x reference)
//
#include <hip/hip_runtime.h>

#define G_N 2048
#define T_N 256

// ws layout (floats) — proven safe (>=1.31MB used since round 1)
#define A_OFF 0
#define B_OFF 262144
#define S_OFF 327680

// out-tail scratch layout (float offsets into d_out)
#define OUT_TOTAL  37748736ull   // 2048*256*8 + 2048*256*64
#define EL         3072          // floats per element {E,F,G}
#define MEND_OFF   36498432ull   // [2048][16][32]
#define HT_OFF     37547008ull   // [256][8][32]
#define PHI_OFF    37612544ull   // [16][32][32]
#define PW2_OFF    37628928ull   // base^(2^k), k=0..4  (5*EL) — contiguous with PHP
#define PHP_OFF    37644288ull   // Phi^(2^j), j=1..3   (3*EL)
#define XT_OFF     37653504ull   // base^s, s=1..16     (16*EL)
#define YT_OFF     37702656ull   // Phi^q,  q=1..15     (15*EL)
#define COVS4_BASE 1048576ull    // covs start in float4 units
#define TAIL4_SKIP 8076032ull    // covs-relative float4 bound (MEND_OFF-4194304)/4

// ---------------------------------------------------------------------------
// helpers
// ---------------------------------------------------------------------------
__device__ __forceinline__ void inv8_wave(int tid, float (*A8)[9], float (*O8)[9]) {
    if (tid < 64) {
        int r = tid >> 3, c = tid & 7;
        float a = A8[r][c];
        float b = (r == c) ? 1.f : 0.f;
#pragma unroll
        for (int j = 0; j < 8; ++j) {
            float ajj = __shfl(a, j * 8 + j, 64);
            float pv = 1.0f / ajj;
            if (r == j) { a *= pv; b *= pv; }
            float ajc = __shfl(a, j * 8 + c, 64);
            float bjc = __shfl(b, j * 8 + c, 64);
            float arj = __shfl(a, r * 8 + j, 64);
            if (r != j) { a -= arj * ajc; b -= arj * bjc; }
        }
        O8[r][c] = b;
    }
}

// 32x32 inverse: pre: AugL=M, AugR=I, Msv=M (all barrier'd). Post: K in AugL.
__device__ __forceinline__ void inv32(int tid, float (*Aug)[66],
                                      float (*Msv)[33], float (*Tmp)[33]) {
    const int r = tid >> 5, c = tid & 31;
    for (int jb = 0; jb < 16; ++jb) {
        const int p0 = 2 * jb, p1 = p0 + 1;
        float a00 = Aug[p0][p0], a01 = Aug[p0][p1], a10 = Aug[p1][p0], a11 = Aug[p1][p1];
        float m0 = Aug[r][p0], m1 = Aug[r][p1];
        float q0 = Aug[p0][c], q1 = Aug[p1][c];
        float q0b = Aug[p0][32 + c], q1b = Aug[p1][32 + c];
        float x0 = Aug[r][c], x1 = Aug[r][32 + c];
        __syncthreads();
        float id = 1.0f / (a00 * a11 - a01 * a10);
        float i00 = a11 * id, i01 = -a01 * id, i10 = -a10 * id, i11 = a00 * id;
        float n0, n1;
        if (r == p0)      { n0 = i00 * q0 + i01 * q1;  n1 = i00 * q0b + i01 * q1b; }
        else if (r == p1) { n0 = i10 * q0 + i11 * q1;  n1 = i10 * q0b + i11 * q1b; }
        else {
            float L0 = m0 * i00 + m1 * i10, L1 = m0 * i01 + m1 * i11;
            n0 = x0 - L0 * q0 - L1 * q1;
            n1 = x1 - L0 * q0b - L1 * q1b;
        }
        Aug[r][c] = n0; Aug[r][32 + c] = n1;
        __syncthreads();
    }
    // Newton-Schulz: K = 2*Kg - Kg*(M*Kg)
    float acc = 0.f;
#pragma unroll
    for (int k = 0; k < 32; ++k) acc += Msv[r][k] * Aug[k][32 + c];
    Tmp[r][c] = acc;
    __syncthreads();
    acc = 0.f;
#pragma unroll
    for (int k = 0; k < 32; ++k) acc += Aug[r][32 + k] * Tmp[k][c];
    float kv = 2.0f * Aug[r][32 + c] - acc;
    __syncthreads();
    Aug[r][c] = kv;
    __syncthreads();
}

// compose(first=a earlier, second=b later): results E''->Msv, F''->T5, G''->T3.
// Never writes Ea..Gb (a may alias b). Ends barrier'd.
__device__ __forceinline__ void compose(int tid,
    float (*Ea)[33], float (*Fa)[33], float (*Ga)[33],
    float (*Eb)[33], float (*Fb)[33], float (*Gb)[33],
    float (*Msv)[33], float (*T1)[33], float (*T3)[33],
    float (*T4)[33], float (*T5)[33], float (*Aug)[66]) {
    const int r = tid >> 5, c = tid & 31;
    float acc = (r == c) ? 1.f : 0.f;
#pragma unroll
    for (int k = 0; k < 32; ++k) acc += Gb[r][k] * Ea[k][c];
    Aug[r][c] = acc; Msv[r][c] = acc; Aug[r][32 + c] = (r == c) ? 1.f : 0.f;
    __syncthreads();
    inv32(tid, Aug, Msv, T4);                   // K = AugL
    // stage A: T1=Ea*K ; T3=Fb*K^T ; T4=K*Gb
    float a1 = 0, a3 = 0, a4 = 0;
#pragma unroll
    for (int k = 0; k < 32; ++k) {
        a1 += Ea[r][k] * Aug[k][c];
        a3 += Fb[r][k] * Aug[c][k];
        a4 += Aug[r][k] * Gb[k][c];
    }
    T1[r][c] = a1; T3[r][c] = a3; T4[r][c] = a4;
    __syncthreads();
    // stage B: Bt(AugR)=Fb*T1 ; T5=T3*Fa
    float b1 = 0, b2 = 0;
#pragma unroll
    for (int k = 0; k < 32; ++k) {
        b1 += Fb[r][k] * T1[k][c];
        b2 += T3[r][k] * Fa[k][c];
    }
    Aug[r][32 + c] = b1; T5[r][c] = b2;
    __syncthreads();
    // stage C: Msv = Eb + Bt*Fb^T ; T1 = Fa^T*T4
    float c1 = Eb[r][c], c2 = 0;
#pragma unroll
    for (int k = 0; k < 32; ++k) {
        c1 += Aug[r][32 + k] * Fb[c][k];
        c2 += Fa[k][r] * T4[k][c];
    }
    __syncthreads();
    Msv[r][c] = c1; T1[r][c] = c2;
    __syncthreads();
    // stage D: T3 = Ga + T1*Fa
    float d1 = Ga[r][c];
#pragma unroll
    for (int k = 0; k < 32; ++k) d1 += T1[r][k] * Fa[k][c];
    __syncthreads();
    T3[r][c] = d1;
    __syncthreads();
}

__device__ __forceinline__ void load_el(const float* g, int tid,
    float (*E)[33], float (*F)[33], float (*G)[33]) {
    const int r = tid >> 5, c = tid & 31;
    E[r][c] = g[tid]; F[r][c] = g[tid + 1024]; G[r][c] = g[tid + 2048];
}
__device__ __forceinline__ void store_el(float* g, int tid,
    float (*E)[33], float (*F)[33], float (*G)[33]) {
    const int r = tid >> 5, c = tid & 31;
    g[tid] = E[r][c]; g[tid + 1024] = F[r][c]; g[tid + 2048] = G[r][c];
}
__device__ __forceinline__ void copy_res_sym(int tid,
    float (*Msv)[33], float (*T5)[33], float (*T3)[33],
    float (*E)[33], float (*F)[33], float (*G)[33]) {
    const int r = tid >> 5, c = tid & 31;
    float e = 0.5f * (Msv[r][c] + Msv[c][r]);
    float f = T5[r][c];
    float gg = 0.5f * (T3[r][c] + T3[c][r]);
    E[r][c] = e; F[r][c] = f; G[r][c] = gg;
    __syncthreads();
}

#define COMPOSE_SHARED \
    __shared__ float Ea[32][33], Fa[32][33], Ga[32][33]; \
    __shared__ float Eb[32][33], Fb[32][33], Gb[32][33]; \
    __shared__ float Msv[32][33], T1[32][33], T3[32][33], T4[32][33], T5[32][33]; \
    __shared__ float Aug[32][66];

// ---------------------------------------------------------------------------
// P1: base element {Q, F, H^T R^-1 H} + squaring chains base^(2^k), Phi^(2^j)
// ---------------------------------------------------------------------------
__global__ __launch_bounds__(1024) void kf_pow1(
    const float* __restrict__ F, const float* __restrict__ H,
    const float* __restrict__ Q, const float* __restrict__ R,
    float* __restrict__ out)
{
    COMPOSE_SHARED
    __shared__ float Rl[8][9], Ri[8][9];
    const int tid = threadIdx.x, r = tid >> 5, c = tid & 31;

    Ea[r][c] = Q[tid];
    Fa[r][c] = F[tid];
    if (tid < 256) T1[tid >> 5][tid & 31] = H[tid];
    if (tid < 64)  Rl[tid >> 3][tid & 7] = R[tid];
    __syncthreads();
    inv8_wave(tid, Rl, Ri);
    __syncthreads();
    if (tid < 256) {                 // RH = R^-1 H  -> T3 rows 0..7
        int m = tid >> 5, j = tid & 31;
        float s = 0.f;
#pragma unroll
        for (int n = 0; n < 8; ++n) s += Ri[m][n] * T1[n][j];
        T3[m][j] = s;
    }
    __syncthreads();
    {                                // G = H^T RH
        float g2 = 0.f;
#pragma unroll
        for (int m = 0; m < 8; ++m) g2 += T1[m][r] * T3[m][c];
        Ga[r][c] = g2;
    }
    __syncthreads();

    float* PW2 = out + PW2_OFF;
    store_el(PW2, tid, Ea, Fa, Ga);
    for (int k = 1; k <= 4; ++k) {   // base^2,4,8,16
        compose(tid, Ea, Fa, Ga, Ea, Fa, Ga, Msv, T1, T3, T4, T5, Aug);
        copy_res_sym(tid, Msv, T5, T3, Ea, Fa, Ga);
        store_el(PW2 + (size_t)k * EL, tid, Ea, Fa, Ga);
    }
    float* PHP = out + PHP_OFF;
    for (int j = 1; j <= 3; ++j) {   // Phi^2,4,8
        compose(tid, Ea, Fa, Ga, Ea, Fa, Ga, Msv, T1, T3, T4, T5, Aug);
        copy_res_sym(tid, Msv, T5, T3, Ea, Fa, Ga);
        store_el(PHP + (size_t)(j - 1) * EL, tid, Ea, Fa, Ga);
    }
}

// ---------------------------------------------------------------------------
// P2: X_s = base^s (blocks 0..15), Y_q = Phi^q (blocks 16..30), binary decomp
// ---------------------------------------------------------------------------
__global__ __launch_bounds__(1024) void kf_pow2(float* __restrict__ out)
{
    COMPOSE_SHARED
    const int tid = threadIdx.x, b = blockIdx.x;
    const int isY = (b >= 16);
    const int val = isY ? (b - 15) : (b + 1);
    const float* tb = out + PW2_OFF + (isY ? 4 * (size_t)EL : 0);  // PW2 / {Phi^(2^j)}
    float* dst = isY ? (out + YT_OFF + (size_t)(b - 16) * EL)
                     : (out + XT_OFF + (size_t)b * EL);

    int bits[5], nb = 0;
    for (int j = 0; j < 5; ++j) if ((val >> j) & 1) bits[nb++] = j;

    load_el(tb + (size_t)bits[0] * EL, tid, Ea, Fa, Ga);
    __syncthreads();
    for (int bi = 1; bi < nb; ++bi) {
        load_el(tb + (size_t)bits[bi] * EL, tid, Eb, Fb, Gb);
        __syncthreads();
        compose(tid, Ea, Fa, Ga, Eb, Fb, Gb, Msv, T1, T3, T4, T5, Aug);
        copy_res_sym(tid, Msv, T5, T3, Ea, Fa, Ga);
    }
    store_el(dst, tid, Ea, Fa, Ga);
}

// ---------------------------------------------------------------------------
// FINAL: per t, prefix[t-1] = Y_q o X_s (one compose), recover P_t, tables.
// ---------------------------------------------------------------------------
__global__ __launch_bounds__(1024) void kf_final(
    const float* __restrict__ Fg, const float* __restrict__ Hg,
    const float* __restrict__ Rg, const float* __restrict__ P0,
    const float* __restrict__ outc, float* __restrict__ ws)
{
    COMPOSE_SHARED
    __shared__ float Hs[8][33], HP[8][33], Wm[8][33], Um[8][33];
    __shared__ float Ss[8][9], Rs[8][9], Si[8][9];
    const int t = blockIdx.x, tid = threadIdx.x, r = tid >> 5, c = tid & 31;

    if (t == 0) {
        Eb[r][c] = P0[tid];          // Pm = P0
        __syncthreads();
    } else {
        const int i = t - 1, s = (i & 15) + 1, q = i >> 4;
        if (q == 0) {
            load_el(outc + XT_OFF + (size_t)(s - 1) * EL, tid, Msv, T5, T3);
            __syncthreads();
        } else {
            load_el(outc + XT_OFF + (size_t)(s - 1) * EL, tid, Ea, Fa, Ga);
            load_el(outc + YT_OFF + (size_t)(q - 1) * EL, tid, Eb, Fb, Gb);
            __syncthreads();
            compose(tid, Ea, Fa, Ga, Eb, Fb, Gb, Msv, T1, T3, T4, T5, Aug);
        }
        // P_t = E + F*(P0*(I+G*P0)^-1)*F^T   (E=Msv, F=T5, G=T3)
        Ea[r][c] = P0[tid];
        __syncthreads();
        float acc = (r == c) ? 1.f : 0.f;
#pragma unroll
        for (int k = 0; k < 32; ++k) acc += T3[r][k] * Ea[k][c];
        Aug[r][c] = acc; T1[r][c] = acc; Aug[r][32 + c] = (r == c) ? 1.f : 0.f;
        __syncthreads();
        inv32(tid, Aug, T1, T4);
        acc = 0.f;
#pragma unroll
        for (int k = 0; k < 32; ++k) acc += Ea[r][k] * Aug[k][c];   // P0*K
        T4[r][c] = acc;
        __syncthreads();
        acc = 0.f;
#pragma unroll
        for (int k = 0; k < 32; ++k) acc += T5[r][k] * T4[k][c];    // F*(P0K)
        Fa[r][c] = acc;
        __syncthreads();
        acc = Msv[r][c];
#pragma unroll
        for (int k = 0; k < 32; ++k) acc += Fa[r][k] * T5[c][k];    // +(..)*F^T
        Ga[r][c] = acc;
        __syncthreads();
        Eb[r][c] = 0.5f * (Ga[r][c] + Ga[c][r]);                    // Pm sym
        __syncthreads();
    }

    // tables from Pm = Eb
    T1[r][c] = Fg[tid];
    if (tid < 256) Hs[tid >> 5][tid & 31] = Hg[tid];
    if (tid < 64)  Rs[tid >> 3][tid & 7] = Rg[tid];
    __syncthreads();
    if (tid < 256) {
        int m = tid >> 5, k2 = tid & 31;
        float a = 0.f;
#pragma unroll
        for (int j = 0; j < 32; ++j) a += Hs[m][j] * Eb[j][k2];
        HP[m][k2] = a;
    }
    __syncthreads();
    if (tid < 64) {
        int m = tid >> 3, n = tid & 7;
        float sv = Rs[m][n];
#pragma unroll
        for (int k = 0; k < 32; ++k) sv += HP[m][k] * Hs[n][k];
        Ss[m][n] = sv;
        ws[S_OFF + (size_t)t * 64 + tid] = sv;
    }
    if (tid >= 256 && tid < 512) {
        int e = tid - 256, m = e >> 5, j = e & 31;
        float wv = 0.f;
#pragma unroll
        for (int k = 0; k < 32; ++k) wv += HP[m][k] * T1[j][k];
        Wm[m][j] = wv;
    }
    __syncthreads();
    inv8_wave(tid, Ss, Si);
    __syncthreads();
    if (tid < 256) {
        int m = tid >> 5, s2 = tid & 31;
        float u = 0.f;
#pragma unroll
        for (int n = 0; n < 8; ++n) u += Si[m][n] * Wm[n][s2];
        Um[m][s2] = u;
        ws[B_OFF + (size_t)t * 256 + s2 * 8 + m] = u;
    }
    __syncthreads();
    {
        float a = T1[r][c];
#pragma unroll
        for (int m = 0; m < 8; ++m) a -= Um[m][r] * Hs[m][c];
        ws[A_OFF + (size_t)t * 1024 + tid] = a;
    }
}

// ---------------------------------------------------------------------------
// TPRE: per chunk c, T_{t0->t} partial products: HT_t = H*T, Phi_c = T(16)
// ---------------------------------------------------------------------------
__global__ __launch_bounds__(1024) void kf_tpre(
    const float* __restrict__ Hg, const float* __restrict__ ws,
    float* __restrict__ out)
{
    __shared__ float Ta[32][33], Tb[32][33], As[32][33], Hs[8][33];
    const int cc = blockIdx.x, tid = threadIdx.x, r = tid >> 5, j = tid & 31;
    const int t0 = 16 * cc;
    float* HT = out + HT_OFF;
    float* PHI = out + PHI_OFF;
    const float* A_tab = ws + A_OFF;

    Ta[r][j] = (r == j) ? 1.f : 0.f;
    if (tid < 256) { Hs[tid >> 5][tid & 31] = Hg[tid]; HT[(size_t)t0 * 256 + tid] = Hg[tid]; }
    __syncthreads();

    float (*cur)[33] = Ta, (*nxt)[33] = Tb;
    for (int k = 1; k <= 16; ++k) {
        As[r][j] = A_tab[(size_t)(t0 + k - 1) * 1024 + tid];
        __syncthreads();
        float a = 0.f;
#pragma unroll
        for (int q = 0; q < 32; ++q) a += As[r][q] * cur[q][j];
        nxt[r][j] = a;
        __syncthreads();
        { float (*tmp)[33] = cur; cur = nxt; nxt = tmp; }
        if (k < 16) {
            if (tid < 256) {
                int m = tid >> 5, s2 = tid & 31;
                float h = 0.f;
#pragma unroll
                for (int j2 = 0; j2 < 32; ++j2) h += Hs[m][j2] * cur[j2][s2];
                HT[(size_t)(t0 + k) * 256 + tid] = h;
            }
        } else {
            PHI[(size_t)cc * 1024 + tid] = cur[r][j];
        }
    }
}

// ---------------------------------------------------------------------------
// M1: per (chunk, 8g) local recursion from zero; emits H*m_loc partials + m_end
// ---------------------------------------------------------------------------
__global__ __launch_bounds__(256) void kf_m1(
    const float* __restrict__ obs, const float* __restrict__ Hg,
    const float* __restrict__ ws, float* __restrict__ out)
{
    __shared__ float As[32][36];
    __shared__ float Bs[32][12];
    const int tid = threadIdx.x, gl = tid >> 5, s = tid & 31;
    const int cc = blockIdx.x >> 8;
    const int gg = blockIdx.x & 255;
    const size_t g = (size_t)gg * 8 + gl;
    const int t0 = 16 * cc;
    const float4* A4 = (const float4*)(ws + A_OFF);
    const float4* B4 = (const float4*)(ws + B_OFF);
    float* means = out;
    float* MEND = out + MEND_OFF;

    float Hreg[32];
#pragma unroll
    for (int k = 0; k < 32; ++k) Hreg[k] = (s < 8) ? Hg[s * 32 + k] : 0.f;

    float m_reg = 0.f;
    float4 a4p = A4[(size_t)t0 * 256 + tid];
    float4 b4p = (tid < 64) ? B4[(size_t)t0 * 64 + tid] : make_float4(0, 0, 0, 0);
    float u_reg = (s < 8) ? obs[(g * 256 + t0) * 8 + s] : 0.f;

    for (int k = 0; k < 16; ++k) {
        const int t = t0 + k;
        { int rr = tid >> 3, c4w = tid & 7; *(float4*)&As[rr][4 * (((2 * rr) ^ c4w) & 7)] = a4p; }
        if (tid < 64) *(float4*)&Bs[tid >> 1][4 * (tid & 1)] = b4p;
        __syncthreads();
        if (k < 15) {
            a4p = A4[(size_t)(t + 1) * 256 + tid];
            if (tid < 64) b4p = B4[(size_t)(t + 1) * 64 + tid];
        }
        float u_next = (k < 15 && s < 8) ? obs[(g * 256 + t + 1) * 8 + s] : 0.f;

        float acc = 0.f, accH = 0.f;
#pragma unroll
        for (int c4 = 0; c4 < 8; ++c4) {
            float4 a = *(const float4*)&As[s][4 * (((2 * s) ^ c4) & 7)];
            float mk0 = __shfl(m_reg, 4 * c4 + 0, 32);
            float mk1 = __shfl(m_reg, 4 * c4 + 1, 32);
            float mk2 = __shfl(m_reg, 4 * c4 + 2, 32);
            float mk3 = __shfl(m_reg, 4 * c4 + 3, 32);
            acc  += a.x * mk0 + a.y * mk1 + a.z * mk2 + a.w * mk3;
            accH += Hreg[4 * c4] * mk0 + Hreg[4 * c4 + 1] * mk1
                  + Hreg[4 * c4 + 2] * mk2 + Hreg[4 * c4 + 3] * mk3;
        }
#pragma unroll
        for (int mm = 0; mm < 8; ++mm) acc += Bs[s][mm] * __shfl(u_reg, mm, 32);

        if (s < 8) means[(g * 256 + t) * 8 + s] = accH;   // partial
        m_reg = acc; u_reg = u_next;
        __syncthreads();
    }
    MEND[(g * 16 + cc) * 32 + s] = m_reg;
}

// ---------------------------------------------------------------------------
// M23: chunk-state prefix per g, then means correction + covs broadcast
// ---------------------------------------------------------------------------
__global__ __launch_bounds__(256) void kf_m23(
    const float* __restrict__ m0, const float* __restrict__ ws,
    float* __restrict__ out)
{
    __shared__ float mst[8][16][32];
    const int tid = threadIdx.x, gl = tid >> 5, s = tid & 31;
    const size_t g = (size_t)blockIdx.x * 8 + gl;
    const float* MEND = out + MEND_OFF;
    const float* HT = out + HT_OFF;
    const float* PHI = out + PHI_OFF;
    float* means = out;
    float4* out4 = (float4*)out;
    const float4* S4 = (const float4*)(ws + S_OFF);

    float msr = m0[g * 32 + s];
    for (int cc = 0; cc < 16; ++cc) {
        mst[gl][cc][s] = msr;
        if (cc < 15) {
            const float4* ph = (const float4*)(PHI + (size_t)cc * 1024 + s * 32);
            float nv = MEND[(g * 16 + cc) * 32 + s];
#pragma unroll
            for (int q4 = 0; q4 < 8; ++q4) {
                float4 p = ph[q4];
                nv += p.x * __shfl(msr, 4 * q4 + 0, 32) + p.y * __shfl(msr, 4 * q4 + 1, 32)
                    + p.z * __shfl(msr, 4 * q4 + 2, 32) + p.w * __shfl(msr, 4 * q4 + 3, 32);
            }
            msr = nv;
        }
    }
    __syncthreads();

    // means correction: lane = (tq in 0..3) * 8 + m
    const int m = s & 7, tq = s >> 3;
    for (int cc = 0; cc < 16; ++cc) {
#pragma unroll
        for (int it = 0; it < 4; ++it) {
            int t = cc * 16 + it * 4 + tq;
            const float4* hr = (const float4*)(HT + (size_t)t * 256 + m * 32);
            float corr = 0.f;
#pragma unroll
            for (int q4 = 0; q4 < 8; ++q4) {
                float4 h = hr[q4];
                corr += h.x * mst[gl][cc][4 * q4] + h.y * mst[gl][cc][4 * q4 + 1]
                      + h.z * mst[gl][cc][4 * q4 + 2] + h.w * mst[gl][cc][4 * q4 + 3];
            }
            means[g * 2048 + (size_t)t * 8 + m] += corr;
        }
    }
    // covs broadcast (skip scratch tail; CLEAN fills it)
    for (int tp = 0; tp < 128; ++tp) {
        int t = 2 * tp + (s >> 4);
        int e4 = s & 15;
        size_t rel4 = (g * 256 + t) * 16 + e4;
        if (rel4 < TAIL4_SKIP) out4[COVS4_BASE + rel4] = S4[t * 16 + e4];
    }
}

// ---------------------------------------------------------------------------
// CLEAN: fill the covs span that was used as scratch
// ---------------------------------------------------------------------------
__global__ void kf_clean(const float* __restrict__ ws, float* __restrict__ out)
{
    float4* out4 = (float4*)out;
    const float4* S4 = (const float4*)(ws + S_OFF);
    const size_t start = COVS4_BASE + TAIL4_SKIP;
    const size_t end = OUT_TOTAL / 4;
    size_t i = start + (size_t)blockIdx.x * blockDim.x + threadIdx.x;
    const size_t stride = (size_t)gridDim.x * blockDim.x;
    for (; i < end; i += stride) {
        size_t rel = i - COVS4_BASE;
        int t = (int)((rel >> 4) & 255);
        int e4 = (int)(rel & 15);
        out4[i] = S4[t * 16 + e4];
    }
}

extern "C" void kernel_launch(void* const* d_in, const int* in_sizes, int n_in,
                              void* d_out, int out_size, void* d_ws, size_t ws_size,
                              hipStream_t stream) {
    const float* obs = (const float*)d_in[0];
    const float* F   = (const float*)d_in[1];
    const float* H   = (const float*)d_in[2];
    const float* Q   = (const float*)d_in[3];
    const float* R   = (const float*)d_in[4];
    const float* m0  = (const float*)d_in[5];
    const float* P0  = (const float*)d_in[6];
    float* out = (float*)d_out;
    float* ws  = (float*)d_ws;

    kf_pow1 <<<1,    1024, 0, stream>>>(F, H, Q, R, out);
    kf_pow2 <<<31,   1024, 0, stream>>>(out);
    kf_final<<<256,  1024, 0, stream>>>(F, H, R, P0, out, ws);
    kf_tpre <<<16,   1024, 0, stream>>>(H, ws, out);
    kf_m1   <<<4096, 256,  0, stream>>>(obs, H, ws, out);
    kf_m23  <<<256,  256,  0, stream>>>(m0, ws, out);
    kf_clean<<<512,  256,  0, stream>>>(ws, out);
}

// Round 6
// 586.356 us; speedup vs baseline: 1.0071x; 1.0071x over previous
//
#include <hip/hip_runtime.h>

#define G_N 2048
#define T_N 256
#define C_N 8          // chunks
#define CH 32          // chunk length

// ws layout (floats)
#define A_OFF 0
#define B_OFF 262144
#define S_OFF 327680

// out-tail scratch (float offsets into d_out); out total = 37748736 floats
#define OUT_TOTAL  37748736ull
#define EL         3072
#define MEND_OFF   37030912ull   // [2048][8][32]
#define HT_OFF     37555200ull   // [256][8][32]
#define PHI_OFF    37620736ull   // [8][32][32]
#define PW2_OFF    37628928ull   // base^(2^k), k=0..4 (5*EL)
#define PHP_OFF    37644288ull   // X^32,64,128 (3*EL) — must be PW2_OFF+5*EL
#define XT_OFF     37653504ull   // base^s, s=1..16
#define YT_OFF     37702656ull   // (X^16)^q, q=1..15
#define COVS4_BASE 1048576ull
#define TAIL4_SKIP 8209152ull    // (MEND_OFF - 4194304)/4

// ---------------- float4 helpers (no operator overloads assumed) -----------
__device__ __forceinline__ float4 f4z() { return make_float4(0.f, 0.f, 0.f, 0.f); }
__device__ __forceinline__ float4 f4madd(float s, const float4 v, float4 a) {
    a.x += s * v.x; a.y += s * v.y; a.z += s * v.z; a.w += s * v.w; return a;
}
__device__ __forceinline__ float dot4(const float4 a, const float4 b) {
    return a.x * b.x + a.y * b.y + a.z * b.z + a.w * b.w;
}

// ---------------- 8x8 inverse on wave 0 (shuffle GJ, SPD) ------------------
__device__ __forceinline__ void inv8_wave(int tid, const float (*A8)[12], float (*O8)[12]) {
    if (tid < 64) {
        int r = tid >> 3, c = tid & 7;
        float a = A8[r][c];
        float b = (r == c) ? 1.f : 0.f;
#pragma unroll
        for (int j = 0; j < 8; ++j) {
            float ajj = __shfl(a, j * 8 + j, 64);
            float pv = 1.0f / ajj;
            if (r == j) { a *= pv; b *= pv; }
            float ajc = __shfl(a, j * 8 + c, 64);
            float bjc = __shfl(b, j * 8 + c, 64);
            float arj = __shfl(a, r * 8 + j, 64);
            if (r != j) { a -= arj * ajc; b -= arj * bjc; }
        }
        O8[r][c] = b;
    }
}

// ---------------- in-register unpivoted 4x4 inverse ------------------------
__device__ __forceinline__ void inv4x4(float P[4][4]) {
#pragma unroll
    for (int j = 0; j < 4; ++j) {
        float pv = 1.0f / P[j][j];
        P[j][j] = pv;
#pragma unroll
        for (int c = 0; c < 4; ++c) if (c != j) P[j][c] *= pv;
#pragma unroll
        for (int r = 0; r < 4; ++r) if (r != j) {
            float f = P[r][j];
#pragma unroll
            for (int c = 0; c < 4; ++c) if (c != j) P[r][c] -= f * P[j][c];
            P[r][j] = -f * pv;
        }
    }
}

// ---------------- 256-thread 32x32 inverse (4x4 pivots + NS) ---------------
// pre: AugL=M, AugR=I, M saved in Msv (all barrier'd). post: K in AugL, barrier'd.
__device__ void inv32_256(int tid, float (*Aug)[72], const float (*Msv)[36], float (*Tmp)[36]) {
    const int r = tid >> 3, c0 = (tid & 7) * 4;
#pragma unroll 1
    for (int jb = 0; jb < 8; ++jb) {
        const int p = 4 * jb;
        float P[4][4];
#pragma unroll
        for (int i = 0; i < 4; ++i)
#pragma unroll
            for (int q = 0; q < 4; ++q) P[i][q] = Aug[p + i][p + q];
        float L[4];
#pragma unroll
        for (int q = 0; q < 4; ++q) L[q] = Aug[r][p + q];
        float4 xl = *(float4*)&Aug[r][c0];
        float4 xr = *(float4*)&Aug[r][36 + c0];
        float4 ql[4], qr[4];
#pragma unroll
        for (int q = 0; q < 4; ++q) {
            ql[q] = *(float4*)&Aug[p + q][c0];
            qr[q] = *(float4*)&Aug[p + q][36 + c0];
        }
        __syncthreads();
        inv4x4(P);
        float4 nl, nr;
        if (r >= p && r < p + 4) {
            int i = r - p;
            nl = f4madd(P[i][3], ql[3], f4madd(P[i][2], ql[2], f4madd(P[i][1], ql[1], f4madd(P[i][0], ql[0], f4z()))));
            nr = f4madd(P[i][3], qr[3], f4madd(P[i][2], qr[2], f4madd(P[i][1], qr[1], f4madd(P[i][0], qr[0], f4z()))));
        } else {
            float LP[4];
#pragma unroll
            for (int q = 0; q < 4; ++q)
                LP[q] = L[0] * P[0][q] + L[1] * P[1][q] + L[2] * P[2][q] + L[3] * P[3][q];
            nl = xl; nr = xr;
#pragma unroll
            for (int q = 0; q < 4; ++q) { nl = f4madd(-LP[q], ql[q], nl); nr = f4madd(-LP[q], qr[q], nr); }
        }
        *(float4*)&Aug[r][c0] = nl;
        *(float4*)&Aug[r][36 + c0] = nr;
        __syncthreads();
    }
    // Newton-Schulz: K = 2*Kg - Kg*(M*Kg)
    float4 acc = f4z();
#pragma unroll
    for (int k = 0; k < 32; ++k) acc = f4madd(Msv[r][k], *(const float4*)&Aug[k][36 + c0], acc);
    *(float4*)&Tmp[r][c0] = acc;
    __syncthreads();
    float4 k4 = *(const float4*)&Aug[r][36 + c0];
    float4 a2 = f4z();
#pragma unroll
    for (int k = 0; k < 32; ++k) a2 = f4madd(Aug[r][36 + k], *(const float4*)&Tmp[k][c0], a2);
    float4 kv = make_float4(2.f * k4.x - a2.x, 2.f * k4.y - a2.y, 2.f * k4.z - a2.z, 2.f * k4.w - a2.w);
    *(float4*)&Aug[r][c0] = kv;
    __syncthreads();
}

// ---------------- matmul fragments (thread = row r, col group c0) ----------
__device__ __forceinline__ float4 mm4(const float (*A)[36], const float (*B)[36], int r, int c0) {
    float4 acc = f4z();
#pragma unroll
    for (int k = 0; k < 32; ++k) acc = f4madd(A[r][k], *(const float4*)&B[k][c0], acc);
    return acc;
}
__device__ __forceinline__ float4 mmTA4(const float (*A)[36], const float (*B)[36], int r, int c0) {
    float4 acc = f4z();                         // A^T * B
#pragma unroll
    for (int k = 0; k < 32; ++k) acc = f4madd(A[k][r], *(const float4*)&B[k][c0], acc);
    return acc;
}
__device__ __forceinline__ float4 mm4K(const float (*A)[36], const float (*Aug)[72], int r, int c0) {
    float4 acc = f4z();                         // A * K (K=AugL)
#pragma unroll
    for (int k = 0; k < 32; ++k) acc = f4madd(A[r][k], *(const float4*)&Aug[k][c0], acc);
    return acc;
}
__device__ __forceinline__ float4 mmK4(const float (*Aug)[72], const float (*B)[36], int r, int c0) {
    float4 acc = f4z();                         // K * B
#pragma unroll
    for (int k = 0; k < 32; ++k) acc = f4madd(Aug[r][k], *(const float4*)&B[k][c0], acc);
    return acc;
}
__device__ __forceinline__ float4 mmKT4(const float (*A)[36], const float (*Aug)[72], int r, int c0) {
    float a0 = 0, a1 = 0, a2 = 0, a3 = 0;       // A * K^T
#pragma unroll
    for (int k = 0; k < 32; ++k) {
        float av = A[r][k];
        a0 += av * Aug[c0 + 0][k]; a1 += av * Aug[c0 + 1][k];
        a2 += av * Aug[c0 + 2][k]; a3 += av * Aug[c0 + 3][k];
    }
    return make_float4(a0, a1, a2, a3);
}

// ---------------- compose (256 threads). Inputs never written. -------------
// result: E''->Msv, F''->T5, G''->T3. Ends barrier'd.
__device__ void compose256(int tid,
    const float (*Ea)[36], const float (*Fa)[36], const float (*Ga)[36],
    const float (*Eb)[36], const float (*Fb)[36], const float (*Gb)[36],
    float (*Msv)[36], float (*T1)[36], float (*T3)[36], float (*T4)[36], float (*T5)[36],
    float (*Aug)[72])
{
    const int r = tid >> 3, c0 = (tid & 7) * 4;
    float4 m4 = mm4(Gb, Ea, r, c0);
    m4.x += (r == c0 + 0) ? 1.f : 0.f; m4.y += (r == c0 + 1) ? 1.f : 0.f;
    m4.z += (r == c0 + 2) ? 1.f : 0.f; m4.w += (r == c0 + 3) ? 1.f : 0.f;
    float4 id4 = make_float4((r == c0 + 0) ? 1.f : 0.f, (r == c0 + 1) ? 1.f : 0.f,
                             (r == c0 + 2) ? 1.f : 0.f, (r == c0 + 3) ? 1.f : 0.f);
    *(float4*)&Aug[r][c0] = m4;
    *(float4*)&Msv[r][c0] = m4;
    *(float4*)&Aug[r][36 + c0] = id4;
    __syncthreads();
    inv32_256(tid, Aug, Msv, T4);               // K in AugL
    // A: T1 = Ea*K ; T4 = K*Gb ; T3 = Fb*K^T
    float4 t1 = mm4K(Ea, Aug, r, c0);
    float4 t4 = mmK4(Aug, Gb, r, c0);
    float4 t3 = mmKT4(Fb, Aug, r, c0);
    *(float4*)&T1[r][c0] = t1; *(float4*)&T4[r][c0] = t4; *(float4*)&T3[r][c0] = t3;
    __syncthreads();
    // B: AugR = Fb*T1 ; T5 = T3*Fa
    float4 bt = mm4(Fb, T1, r, c0);
    float4 t5 = mm4(T3, Fa, r, c0);
    *(float4*)&Aug[r][36 + c0] = bt; *(float4*)&T5[r][c0] = t5;
    __syncthreads();
    // C: Msv = Eb + AugR*Fb^T ; T1 = Fa^T*T4
    {
        float4 ev = *(const float4*)&Eb[r][c0];
        float s0 = 0, s1 = 0, s2 = 0, s3 = 0;
#pragma unroll
        for (int k = 0; k < 32; ++k) {
            float av = Aug[r][36 + k];
            s0 += av * Fb[c0 + 0][k]; s1 += av * Fb[c0 + 1][k];
            s2 += av * Fb[c0 + 2][k]; s3 += av * Fb[c0 + 3][k];
        }
        ev.x += s0; ev.y += s1; ev.z += s2; ev.w += s3;
        float4 t1n = mmTA4(Fa, T4, r, c0);
        *(float4*)&Msv[r][c0] = ev;
        *(float4*)&T1[r][c0] = t1n;
    }
    __syncthreads();
    // D: T3 = Ga + T1*Fa
    {
        float4 g4 = mm4(T1, Fa, r, c0);
        float4 ga = *(const float4*)&Ga[r][c0];
        g4.x += ga.x; g4.y += ga.y; g4.z += ga.z; g4.w += ga.w;
        *(float4*)&T3[r][c0] = g4;
    }
    __syncthreads();
}

__device__ __forceinline__ void load_el256(const float* g, int tid,
    float (*E)[36], float (*F)[36], float (*G)[36]) {
    const int r = tid >> 3, c0 = (tid & 7) * 4;
    *(float4*)&E[r][c0] = *(const float4*)&g[tid * 4];
    *(float4*)&F[r][c0] = *(const float4*)&g[1024 + tid * 4];
    *(float4*)&G[r][c0] = *(const float4*)&g[2048 + tid * 4];
}
__device__ __forceinline__ void store_el256(float* g, int tid,
    const float (*E)[36], const float (*F)[36], const float (*G)[36]) {
    const int r = tid >> 3, c0 = (tid & 7) * 4;
    *(float4*)&g[tid * 4]        = *(const float4*)&E[r][c0];
    *(float4*)&g[1024 + tid * 4] = *(const float4*)&F[r][c0];
    *(float4*)&g[2048 + tid * 4] = *(const float4*)&G[r][c0];
}
__device__ void copy_res_sym256(int tid, const float (*Msv)[36], const float (*T5)[36],
    const float (*T3)[36], float (*E)[36], float (*F)[36], float (*G)[36]) {
    const int r = tid >> 3, c0 = (tid & 7) * 4;
    float4 f = *(const float4*)&T5[r][c0];
    float4 e, g;
    e.x = 0.5f * (Msv[r][c0 + 0] + Msv[c0 + 0][r]); e.y = 0.5f * (Msv[r][c0 + 1] + Msv[c0 + 1][r]);
    e.z = 0.5f * (Msv[r][c0 + 2] + Msv[c0 + 2][r]); e.w = 0.5f * (Msv[r][c0 + 3] + Msv[c0 + 3][r]);
    g.x = 0.5f * (T3[r][c0 + 0] + T3[c0 + 0][r]); g.y = 0.5f * (T3[r][c0 + 1] + T3[c0 + 1][r]);
    g.z = 0.5f * (T3[r][c0 + 2] + T3[c0 + 2][r]); g.w = 0.5f * (T3[r][c0 + 3] + T3[c0 + 3][r]);
    *(float4*)&E[r][c0] = e; *(float4*)&F[r][c0] = f; *(float4*)&G[r][c0] = g;
    __syncthreads();
}

#define COMPOSE_SHARED \
    __shared__ float Ea[32][36], Fa[32][36], Ga[32][36]; \
    __shared__ float Eb[32][36], Fb[32][36], Gb[32][36]; \
    __shared__ float Msv[32][36], T1[32][36], T3[32][36], T4[32][36], T5[32][36]; \
    __shared__ float Aug[32][72];

// ---------------------------------------------------------------------------
// P1: base element {Q, F, H^T R^-1 H}, then X^2..X^16 and X^32,64,128
// ---------------------------------------------------------------------------
__global__ __launch_bounds__(256) void kf_pow1(
    const float* __restrict__ F, const float* __restrict__ H,
    const float* __restrict__ Q, const float* __restrict__ R,
    float* __restrict__ out)
{
    COMPOSE_SHARED
    __shared__ float Hs[8][36], RHs[8][36], Rl[8][12], Ri[8][12];
    const int tid = threadIdx.x, r = tid >> 3, c0 = (tid & 7) * 4;

    *(float4*)&Ea[r][c0] = *(const float4*)&Q[tid * 4];
    *(float4*)&Fa[r][c0] = *(const float4*)&F[tid * 4];
    if (tid < 64) *(float4*)&Hs[tid >> 3][(tid & 7) * 4] = *(const float4*)&H[tid * 4];
    if (tid < 64) Rl[tid >> 3][tid & 7] = R[tid];
    __syncthreads();
    inv8_wave(tid, Rl, Ri);
    __syncthreads();
    {   // RH = R^-1 * H  (8x32, one output/thread)
        int m = tid >> 5, jj = tid & 31;
        float s = 0.f;
#pragma unroll
        for (int n = 0; n < 8; ++n) s += Ri[m][n] * Hs[n][jj];
        RHs[m][jj] = s;
    }
    __syncthreads();
    {   // G = H^T * RH  (4/thread)
        float4 acc = f4z();
#pragma unroll
        for (int m = 0; m < 8; ++m) acc = f4madd(Hs[m][r], *(const float4*)&RHs[m][c0], acc);
        *(float4*)&Ga[r][c0] = acc;
    }
    __syncthreads();

    float* PW2 = out + PW2_OFF;
    store_el256(PW2, tid, Ea, Fa, Ga);
    for (int k = 1; k <= 4; ++k) {
        compose256(tid, Ea, Fa, Ga, Ea, Fa, Ga, Msv, T1, T3, T4, T5, Aug);
        copy_res_sym256(tid, Msv, T5, T3, Ea, Fa, Ga);
        store_el256(PW2 + (size_t)k * EL, tid, Ea, Fa, Ga);
    }
    float* PHP = out + PHP_OFF;
    for (int j = 1; j <= 3; ++j) {
        compose256(tid, Ea, Fa, Ga, Ea, Fa, Ga, Msv, T1, T3, T4, T5, Aug);
        copy_res_sym256(tid, Msv, T5, T3, Ea, Fa, Ga);
        store_el256(PHP + (size_t)(j - 1) * EL, tid, Ea, Fa, Ga);
    }
}

// ---------------------------------------------------------------------------
// P2: X^s (blocks 0..15) and (X^16)^q (blocks 16..30) by binary decomposition
// ---------------------------------------------------------------------------
__global__ __launch_bounds__(256) void kf_pow2(float* __restrict__ out)
{
    COMPOSE_SHARED
    const int tid = threadIdx.x, b = blockIdx.x;
    const int isY = (b >= 16);
    const int val = isY ? (b - 15) : (b + 1);
    const float* tb = out + PW2_OFF + (isY ? 4 * (size_t)EL : 0);
    float* dst = isY ? (out + YT_OFF + (size_t)(b - 16) * EL)
                     : (out + XT_OFF + (size_t)b * EL);

    int bits[5], nb = 0;
    for (int j = 0; j < 5; ++j) if ((val >> j) & 1) bits[nb++] = j;

    load_el256(tb + (size_t)bits[0] * EL, tid, Ea, Fa, Ga);
    __syncthreads();
    for (int bi = 1; bi < nb; ++bi) {
        load_el256(tb + (size_t)bits[bi] * EL, tid, Eb, Fb, Gb);
        __syncthreads();
        compose256(tid, Ea, Fa, Ga, Eb, Fb, Gb, Msv, T1, T3, T4, T5, Aug);
        copy_res_sym256(tid, Msv, T5, T3, Ea, Fa, Ga);
    }
    store_el256(dst, tid, Ea, Fa, Ga);
}

// ---------------------------------------------------------------------------
// FINAL: per t, prefix = Y_q o X^s, recover P_t, build A_t/B_t/S_t tables
// ---------------------------------------------------------------------------
__global__ __launch_bounds__(256) void kf_final(
    const float* __restrict__ Fg, const float* __restrict__ Hg,
    const float* __restrict__ Rg, const float* __restrict__ P0,
    const float* __restrict__ outc, float* __restrict__ ws)
{
    COMPOSE_SHARED
    __shared__ float Hs[8][36], HPs[8][36], Wms[8][36], Ums[8][36];
    __shared__ float Ss[8][12], Rs[8][12], Sis[8][12];
    const int t = blockIdx.x, tid = threadIdx.x, r = tid >> 3, c0 = (tid & 7) * 4;

    if (t == 0) {
        *(float4*)&Eb[r][c0] = *(const float4*)&P0[tid * 4];
        __syncthreads();
    } else {
        const int i = t - 1, s = (i & 15) + 1, q = i >> 4;
        if (q == 0) {
            load_el256(outc + XT_OFF + (size_t)(s - 1) * EL, tid, Msv, T5, T3);
            __syncthreads();
        } else {
            load_el256(outc + XT_OFF + (size_t)(s - 1) * EL, tid, Ea, Fa, Ga);
            load_el256(outc + YT_OFF + (size_t)(q - 1) * EL, tid, Eb, Fb, Gb);
            __syncthreads();
            compose256(tid, Ea, Fa, Ga, Eb, Fb, Gb, Msv, T1, T3, T4, T5, Aug);
        }
        // P_t = E + F*(P0*(I+G*P0)^-1)*F^T    (E=Msv, F=T5, G=T3)
        *(float4*)&Ea[r][c0] = *(const float4*)&P0[tid * 4];
        __syncthreads();
        {
            float4 m4 = mm4(T3, Ea, r, c0);
            m4.x += (r == c0 + 0) ? 1.f : 0.f; m4.y += (r == c0 + 1) ? 1.f : 0.f;
            m4.z += (r == c0 + 2) ? 1.f : 0.f; m4.w += (r == c0 + 3) ? 1.f : 0.f;
            float4 id4 = make_float4((r == c0 + 0) ? 1.f : 0.f, (r == c0 + 1) ? 1.f : 0.f,
                                     (r == c0 + 2) ? 1.f : 0.f, (r == c0 + 3) ? 1.f : 0.f);
            *(float4*)&Aug[r][c0] = m4; *(float4*)&T4[r][c0] = m4;
            *(float4*)&Aug[r][36 + c0] = id4;
        }
        __syncthreads();
        inv32_256(tid, Aug, T4, T1);            // K in AugL
        *(float4*)&T1[r][c0] = mm4K(Ea, Aug, r, c0);      // P0*K
        __syncthreads();
        *(float4*)&T4[r][c0] = mm4(T5, T1, r, c0);        // F*(P0K)
        __syncthreads();
        {   // Fa(temp) = Msv + T4*T5^T
            float4 ev = *(const float4*)&Msv[r][c0];
            float s0 = 0, s1 = 0, s2 = 0, s3 = 0;
#pragma unroll
            for (int k = 0; k < 32; ++k) {
                float av = T4[r][k];
                s0 += av * T5[c0 + 0][k]; s1 += av * T5[c0 + 1][k];
                s2 += av * T5[c0 + 2][k]; s3 += av * T5[c0 + 3][k];
            }
            ev.x += s0; ev.y += s1; ev.z += s2; ev.w += s3;
            *(float4*)&Fa[r][c0] = ev;
        }
        __syncthreads();
        {   // Pm symmetrized -> Eb
            float4 e;
            e.x = 0.5f * (Fa[r][c0 + 0] + Fa[c0 + 0][r]); e.y = 0.5f * (Fa[r][c0 + 1] + Fa[c0 + 1][r]);
            e.z = 0.5f * (Fa[r][c0 + 2] + Fa[c0 + 2][r]); e.w = 0.5f * (Fa[r][c0 + 3] + Fa[c0 + 3][r]);
            *(float4*)&Eb[r][c0] = e;
        }
        __syncthreads();
    }

    // ---- tables from Pm = Eb ----
    *(float4*)&Fa[r][c0] = *(const float4*)&Fg[tid * 4];
    if (tid < 64) *(float4*)&Hs[tid >> 3][(tid & 7) * 4] = *(const float4*)&Hg[tid * 4];
    if (tid < 64) Rs[tid >> 3][tid & 7] = Rg[tid];
    __syncthreads();
    {   // HP = H*Pm (8x32, 1/thread)
        int m = tid >> 5, k2 = tid & 31;
        float a = 0.f;
#pragma unroll
        for (int j = 0; j < 32; ++j) a += Hs[m][j] * Eb[j][k2];
        HPs[m][k2] = a;
    }
    __syncthreads();
    {   // W = HP*F^T (all threads); S = HP*H^T + R (tid<64)
        int m = tid >> 5, jj = tid & 31;
        float wv = 0.f;
#pragma unroll
        for (int k = 0; k < 32; ++k) wv += HPs[m][k] * Fa[jj][k];
        Wms[m][jj] = wv;
        if (tid < 64) {
            int mm = tid >> 3, n = tid & 7;
            float sv = Rs[mm][n];
#pragma unroll
            for (int k = 0; k < 32; ++k) sv += HPs[mm][k] * Hs[n][k];
            Ss[mm][n] = sv;
            ws[S_OFF + (size_t)t * 64 + tid] = sv;
        }
    }
    __syncthreads();
    inv8_wave(tid, Ss, Sis);
    __syncthreads();
    {   // U = Si*W ; B_tab[t][s][m] = U[m][s]
        int m = tid >> 5, s2 = tid & 31;
        float u = 0.f;
#pragma unroll
        for (int n = 0; n < 8; ++n) u += Sis[m][n] * Wms[n][s2];
        Ums[m][s2] = u;
        ws[B_OFF + (size_t)t * 256 + s2 * 8 + m] = u;
    }
    __syncthreads();
    {   // A = F - U^T*H  (4/thread, float4 store)
        float4 a4 = *(const float4*)&Fa[r][c0];
#pragma unroll
        for (int m = 0; m < 8; ++m) {
            float um = Ums[m][r];
            a4 = f4madd(-um, *(const float4*)&Hs[m][c0], a4);
        }
        *(float4*)&((float4*)(ws + A_OFF))[(size_t)t * 256 + tid] = a4;
    }
}

// ---------------------------------------------------------------------------
// TPRE: per chunk (8 blocks), 32 serial steps: HT_t = H*T_{t0->t}, PHI_c
// ---------------------------------------------------------------------------
__global__ __launch_bounds__(256) void kf_tpre(
    const float* __restrict__ Hg, const float* __restrict__ ws,
    float* __restrict__ out)
{
    __shared__ float Ta[32][36], Tb[32][36], As[32][36], Hs[8][36];
    const int cc = blockIdx.x, tid = threadIdx.x, r = tid >> 3, c0 = (tid & 7) * 4;
    const int t0 = CH * cc;
    float* HT = out + HT_OFF;
    float* PHI = out + PHI_OFF;
    const float4* A4 = (const float4*)(ws + A_OFF);

    {   // Ta = I
        float4 id4 = make_float4((r == c0 + 0) ? 1.f : 0.f, (r == c0 + 1) ? 1.f : 0.f,
                                 (r == c0 + 2) ? 1.f : 0.f, (r == c0 + 3) ? 1.f : 0.f);
        *(float4*)&Ta[r][c0] = id4;
    }
    if (tid < 64) *(float4*)&Hs[tid >> 3][(tid & 7) * 4] = *(const float4*)&Hg[tid * 4];
    HT[(size_t)t0 * 256 + tid] = Hg[tid & 255];     // HT[t0] = H
    *(float4*)&As[r][c0] = A4[(size_t)t0 * 256 + tid];
    __syncthreads();

    float (*cur)[36] = Ta, (*nxt)[36] = Tb;
    for (int k = 1; k <= CH; ++k) {
        *(float4*)&nxt[r][c0] = mm4(As, cur, r, c0);
        __syncthreads();
        if (k < CH) {
            int m = tid >> 5, s2 = tid & 31;
            float h = 0.f;
#pragma unroll
            for (int j = 0; j < 32; ++j) h += Hs[m][j] * nxt[j][s2];
            HT[(size_t)(t0 + k) * 256 + tid] = h;
            *(float4*)&As[r][c0] = A4[(size_t)(t0 + k) * 256 + tid];
        } else {
            *(float4*)&((float4*)PHI)[(size_t)cc * 256 + tid] = *(const float4*)&nxt[r][c0];
        }
        __syncthreads();
        float (*tmp)[36] = cur; cur = nxt; nxt = tmp;
    }
}

// ---------------------------------------------------------------------------
// M1: one-wave blocks; A_t/B_t/H in registers, m in LDS; zero barriers.
// 2048 blocks = 8 chunks x 256 g-groups (8 g each), 32 steps.
// ---------------------------------------------------------------------------
__global__ __launch_bounds__(64) void kf_m1(
    const float* __restrict__ obs, const float* __restrict__ Hg,
    const float* __restrict__ ws, float* __restrict__ out)
{
    __shared__ float mc[8][36];
    __shared__ float us[8][12];
    const int lane = threadIdx.x;
    const int rA = lane >> 1, hA = lane & 1;
    const int rH = lane >> 3, cH = lane & 7;
    const int cc = blockIdx.x >> 8;
    const int gb = (blockIdx.x & 255) * 8;
    const int t0 = cc * CH;
    const float4* A4 = (const float4*)(ws + A_OFF);
    const float4* B4 = (const float4*)(ws + B_OFF);
    const float4* obs4 = (const float4*)obs;
    float* means = out;
    float* MEND = out + MEND_OFF;

    const float4 h4 = *(const float4*)&Hg[rH * 32 + cH * 4];

    {   // zero m
        float* mf = &mc[0][0];
        for (int i = lane; i < 8 * 36; i += 64) mf[i] = 0.f;
    }

    float4 an0 = A4[(size_t)t0 * 256 + lane * 4 + 0];
    float4 an1 = A4[(size_t)t0 * 256 + lane * 4 + 1];
    float4 an2 = A4[(size_t)t0 * 256 + lane * 4 + 2];
    float4 an3 = A4[(size_t)t0 * 256 + lane * 4 + 3];
    float4 bn  = B4[(size_t)t0 * 64 + lane];
    float4 un = f4z();
    if (lane < 16) un = obs4[((size_t)(gb + (lane >> 1)) * 256 + t0) * 2 + (lane & 1)];

    for (int k = 0; k < CH; ++k) {
        const int t = t0 + k;
        const float4 a0 = an0, a1 = an1, a2 = an2, a3 = an3, bb = bn;
        if (lane < 16) *(float4*)&us[lane >> 1][(lane & 1) * 4] = un;
        if (k < CH - 1) {
            an0 = A4[(size_t)(t + 1) * 256 + lane * 4 + 0];
            an1 = A4[(size_t)(t + 1) * 256 + lane * 4 + 1];
            an2 = A4[(size_t)(t + 1) * 256 + lane * 4 + 2];
            an3 = A4[(size_t)(t + 1) * 256 + lane * 4 + 3];
            bn  = B4[(size_t)(t + 1) * 64 + lane];
            if (lane < 16) un = obs4[((size_t)(gb + (lane >> 1)) * 256 + t + 1) * 2 + (lane & 1)];
        }
#pragma unroll 1
        for (int gl = 0; gl < 8; ++gl) {
            // means (H * m_prior): partial + 3-level reduce over lane&7
            float4 mh = *(const float4*)&mc[gl][cH * 4];
            float hp = dot4(h4, mh);
            hp += __shfl_xor(hp, 1);
            hp += __shfl_xor(hp, 2);
            hp += __shfl_xor(hp, 4);
            // m_next = A*m + B*u  (half-row per lane, pair-combine)
            float4 m0v = *(const float4*)&mc[gl][hA * 16 + 0];
            float4 m1v = *(const float4*)&mc[gl][hA * 16 + 4];
            float4 m2v = *(const float4*)&mc[gl][hA * 16 + 8];
            float4 m3v = *(const float4*)&mc[gl][hA * 16 + 12];
            float d = dot4(a0, m0v) + dot4(a1, m1v) + dot4(a2, m2v) + dot4(a3, m3v);
            float4 u4 = *(const float4*)&us[gl][hA * 4];
            d += dot4(bb, u4);
            d += __shfl_xor(d, 1);
            if ((lane & 7) == 0) means[((size_t)(gb + gl) * 256 + t) * 8 + rH] = hp;
            if (hA == 0) mc[gl][rA] = d;
        }
    }
#pragma unroll 1
    for (int gl = 0; gl < 8; ++gl)
        if (hA == 0) MEND[((size_t)(gb + gl) * 8 + cc) * 32 + rA] = mc[gl][rA];
}

// ---------------------------------------------------------------------------
// M23: chunk-state prefix per g, means correction, covs broadcast
// ---------------------------------------------------------------------------
__global__ __launch_bounds__(256) void kf_m23(
    const float* __restrict__ m0, const float* __restrict__ ws,
    float* __restrict__ out)
{
    __shared__ float mst[8][8][36];
    const int tid = threadIdx.x, gl = tid >> 5, s = tid & 31;
    const size_t g = (size_t)blockIdx.x * 8 + gl;
    const float* MEND = out + MEND_OFF;
    const float4* HT4 = (const float4*)(out + HT_OFF);
    const float4* PHI4 = (const float4*)(out + PHI_OFF);
    float* means = out;
    float4* out4 = (float4*)out;
    const float4* S4 = (const float4*)(ws + S_OFF);

    float msr = m0[g * 32 + s];
    for (int cc = 0; cc < C_N; ++cc) {
        mst[gl][cc][s] = msr;
        if (cc < C_N - 1) {
            float nv = MEND[(g * 8 + cc) * 32 + s];
#pragma unroll
            for (int q4 = 0; q4 < 8; ++q4) {
                float4 p = PHI4[cc * 256 + s * 8 + q4];
                nv += p.x * __shfl(msr, 4 * q4 + 0, 32) + p.y * __shfl(msr, 4 * q4 + 1, 32)
                    + p.z * __shfl(msr, 4 * q4 + 2, 32) + p.w * __shfl(msr, 4 * q4 + 3, 32);
            }
            msr = nv;
        }
    }
    __syncthreads();

    const int m = s & 7, tq = s >> 3;
    for (int cc = 0; cc < C_N; ++cc) {
        const float* mrow = &mst[gl][cc][0];
#pragma unroll
        for (int it = 0; it < 8; ++it) {
            int t = cc * CH + it * 4 + tq;
            float corr = 0.f;
#pragma unroll
            for (int q4 = 0; q4 < 8; ++q4) {
                float4 h = HT4[(size_t)t * 64 + m * 8 + q4];
                const float4 mm = *(const float4*)&mrow[4 * q4];
                corr += dot4(h, mm);
            }
            means[g * 2048 + (size_t)t * 8 + m] += corr;
        }
    }
    // covs broadcast (skip scratch tail; CLEAN fills it)
    for (int tp = 0; tp < 128; ++tp) {
        int t = 2 * tp + (s >> 4);
        int e4 = s & 15;
        size_t rel4 = (g * 256 + t) * 16 + e4;
        if (rel4 < TAIL4_SKIP) out4[COVS4_BASE + rel4] = S4[t * 16 + e4];
    }
}

// ---------------------------------------------------------------------------
// CLEAN: fill the covs span that was used as scratch
// ---------------------------------------------------------------------------
__global__ void kf_clean(const float* __restrict__ ws, float* __restrict__ out)
{
    float4* out4 = (float4*)out;
    const float4* S4 = (const float4*)(ws + S_OFF);
    const size_t start = COVS4_BASE + TAIL4_SKIP;
    const size_t end = OUT_TOTAL / 4;
    size_t i = start + (size_t)blockIdx.x * blockDim.x + threadIdx.x;
    const size_t stride = (size_t)gridDim.x * blockDim.x;
    for (; i < end; i += stride) {
        size_t rel = i - COVS4_BASE;
        int t = (int)((rel >> 4) & 255);
        int e4 = (int)(rel & 15);
        out4[i] = S4[t * 16 + e4];
    }
}

extern "C" void kernel_launch(void* const* d_in, const int* in_sizes, int n_in,
                              void* d_out, int out_size, void* d_ws, size_t ws_size,
                              hipStream_t stream) {
    const float* obs = (const float*)d_in[0];
    const float* F   = (const float*)d_in[1];
    const float* H   = (const float*)d_in[2];
    const float* Q   = (const float*)d_in[3];
    const float* R   = (const float*)d_in[4];
    const float* m0  = (const float*)d_in[5];
    const float* P0  = (const float*)d_in[6];
    float* out = (float*)d_out;
    float* ws  = (float*)d_ws;

    kf_pow1 <<<1,    256, 0, stream>>>(F, H, Q, R, out);
    kf_pow2 <<<31,   256, 0, stream>>>(out);
    kf_final<<<256,  256, 0, stream>>>(F, H, R, P0, out, ws);
    kf_tpre <<<8,    256, 0, stream>>>(H, ws, out);
    kf_m1   <<<2048, 64,  0, stream>>>(obs, H, ws, out);
    kf_m23  <<<256,  256, 0, stream>>>(m0, ws, out);
    kf_clean<<<512,  256, 0, stream>>>(ws, out);
}

// Round 7
// 477.987 us; speedup vs baseline: 1.2354x; 1.2267x over previous
//
#include <hip/hip_runtime.h>

#define G_N 2048
#define T_N 256
#define C_N 8          // chunks
#define CH 32          // chunk length

// ws layout (floats)
#define A_OFF 0
#define B_OFF 262144
#define S_OFF 327680

// out-tail scratch (float offsets into d_out); out total = 37748736 floats
#define OUT_TOTAL  37748736ull
#define EL         3072
#define MEND_OFF   37030912ull   // [2048][8][32]
#define HT_OFF     37555200ull   // [256][8][32]
#define PHI_OFF    37620736ull   // [8][32][32]
#define XT_OFF     37653504ull   // X^s at slot s-1, s=1..16 (16*EL)
#define YT_OFF     37702656ull   // Y^q at slot q-2, q=2..15 (14*EL)
#define COVS4_BASE 1048576ull

struct LvlTasks { int4 t[8]; };   // x=dst slot, y=srcA slot, z=srcB slot

// ---------------- float4 helpers ------------------------------------------
__device__ __forceinline__ float4 f4z() { return make_float4(0.f, 0.f, 0.f, 0.f); }
__device__ __forceinline__ float4 f4madd(float s, const float4 v, float4 a) {
    a.x += s * v.x; a.y += s * v.y; a.z += s * v.z; a.w += s * v.w; return a;
}
__device__ __forceinline__ float dot4(const float4 a, const float4 b) {
    return a.x * b.x + a.y * b.y + a.z * b.z + a.w * b.w;
}

// slot -> global pointer
__device__ __forceinline__ const float* slot_c(const float* out, int s) {
    return out + ((s < 16) ? (XT_OFF + (size_t)s * EL) : (YT_OFF + (size_t)(s - 16) * EL));
}
__device__ __forceinline__ float* slot_w(float* out, int s) {
    return out + ((s < 16) ? (XT_OFF + (size_t)s * EL) : (YT_OFF + (size_t)(s - 16) * EL));
}

// ---------------- 8x8 inverse on wave 0 (shuffle GJ, SPD) ------------------
__device__ __forceinline__ void inv8_wave(int tid, const float (*A8)[12], float (*O8)[12]) {
    if (tid < 64) {
        int r = tid >> 3, c = tid & 7;
        float a = A8[r][c];
        float b = (r == c) ? 1.f : 0.f;
#pragma unroll
        for (int j = 0; j < 8; ++j) {
            float ajj = __shfl(a, j * 8 + j, 64);
            float pv = 1.0f / ajj;
            if (r == j) { a *= pv; b *= pv; }
            float ajc = __shfl(a, j * 8 + c, 64);
            float bjc = __shfl(b, j * 8 + c, 64);
            float arj = __shfl(a, r * 8 + j, 64);
            if (r != j) { a -= arj * ajc; b -= arj * bjc; }
        }
        O8[r][c] = b;
    }
}

// ---------------- in-register unpivoted 4x4 inverse ------------------------
__device__ __forceinline__ void inv4x4(float P[4][4]) {
#pragma unroll
    for (int j = 0; j < 4; ++j) {
        float pv = 1.0f / P[j][j];
        P[j][j] = pv;
#pragma unroll
        for (int c = 0; c < 4; ++c) if (c != j) P[j][c] *= pv;
#pragma unroll
        for (int r = 0; r < 4; ++r) if (r != j) {
            float f = P[r][j];
#pragma unroll
            for (int c = 0; c < 4; ++c) if (c != j) P[r][c] -= f * P[j][c];
            P[r][j] = -f * pv;
        }
    }
}

// ---------------- 256-thread 32x32 inverse (4x4 pivots + NS) ---------------
// pre: AugL=M, AugR=I, M saved in Msv (barrier'd).
// post: K in AugL, K^T in AugR, barrier'd.
__device__ void inv32_256(int tid, float (*Aug)[72], const float (*Msv)[36], float (*Tmp)[36]) {
    const int r = tid >> 3, c0 = (tid & 7) * 4;
#pragma unroll 1
    for (int jb = 0; jb < 8; ++jb) {
        const int p = 4 * jb;
        float P[4][4];
#pragma unroll
        for (int i = 0; i < 4; ++i)
#pragma unroll
            for (int q = 0; q < 4; ++q) P[i][q] = Aug[p + i][p + q];
        float L[4];
#pragma unroll
        for (int q = 0; q < 4; ++q) L[q] = Aug[r][p + q];
        float4 xl = *(float4*)&Aug[r][c0];
        float4 xr = *(float4*)&Aug[r][36 + c0];
        float4 ql[4], qr[4];
#pragma unroll
        for (int q = 0; q < 4; ++q) {
            ql[q] = *(float4*)&Aug[p + q][c0];
            qr[q] = *(float4*)&Aug[p + q][36 + c0];
        }
        __syncthreads();
        inv4x4(P);
        float4 nl, nr;
        if (r >= p && r < p + 4) {
            int i = r - p;
            nl = f4madd(P[i][3], ql[3], f4madd(P[i][2], ql[2], f4madd(P[i][1], ql[1], f4madd(P[i][0], ql[0], f4z()))));
            nr = f4madd(P[i][3], qr[3], f4madd(P[i][2], qr[2], f4madd(P[i][1], qr[1], f4madd(P[i][0], qr[0], f4z()))));
        } else {
            float LP[4];
#pragma unroll
            for (int q = 0; q < 4; ++q)
                LP[q] = L[0] * P[0][q] + L[1] * P[1][q] + L[2] * P[2][q] + L[3] * P[3][q];
            nl = xl; nr = xr;
#pragma unroll
            for (int q = 0; q < 4; ++q) { nl = f4madd(-LP[q], ql[q], nl); nr = f4madd(-LP[q], qr[q], nr); }
        }
        *(float4*)&Aug[r][c0] = nl;
        *(float4*)&Aug[r][36 + c0] = nr;
        __syncthreads();
    }
    // Newton-Schulz: K = 2*Kg - Kg*(M*Kg)
    float4 acc = f4z();
#pragma unroll
    for (int k = 0; k < 32; ++k) acc = f4madd(Msv[r][k], *(const float4*)&Aug[k][36 + c0], acc);
    *(float4*)&Tmp[r][c0] = acc;
    __syncthreads();
    float4 k4 = *(const float4*)&Aug[r][36 + c0];
    float4 a2 = f4z();
#pragma unroll
    for (int k = 0; k < 32; ++k) a2 = f4madd(Aug[r][36 + k], *(const float4*)&Tmp[k][c0], a2);
    float4 kv = make_float4(2.f * k4.x - a2.x, 2.f * k4.y - a2.y, 2.f * k4.z - a2.z, 2.f * k4.w - a2.w);
    __syncthreads();                          // all AugR reads complete
    *(float4*)&Aug[r][c0] = kv;               // K
    Aug[c0 + 0][36 + r] = kv.x;               // K^T into AugR
    Aug[c0 + 1][36 + r] = kv.y;
    Aug[c0 + 2][36 + r] = kv.z;
    Aug[c0 + 3][36 + r] = kv.w;
    __syncthreads();
}

// ---------------- matmul fragments (row-broadcast, conflict-free) ----------
__device__ __forceinline__ float4 mm4(const float (*A)[36], const float (*B)[36], int r, int c0) {
    float4 acc = f4z();
#pragma unroll
    for (int k = 0; k < 32; ++k) acc = f4madd(A[r][k], *(const float4*)&B[k][c0], acc);
    return acc;
}
__device__ __forceinline__ float4 mm4K(const float (*A)[36], const float (*Aug)[72], int r, int c0) {
    float4 acc = f4z();                       // A * K (K = AugL)
#pragma unroll
    for (int k = 0; k < 32; ++k) acc = f4madd(A[r][k], *(const float4*)&Aug[k][c0], acc);
    return acc;
}
__device__ __forceinline__ float4 mmK4(const float (*Aug)[72], const float (*B)[36], int r, int c0) {
    float4 acc = f4z();                       // K * B
#pragma unroll
    for (int k = 0; k < 32; ++k) acc = f4madd(Aug[r][k], *(const float4*)&B[k][c0], acc);
    return acc;
}
__device__ __forceinline__ float4 mm4R(const float (*A)[36], const float (*Aug)[72], int r, int c0) {
    float4 acc = f4z();                       // A * (AugR) ; AugR holds K^T
#pragma unroll
    for (int k = 0; k < 32; ++k) acc = f4madd(A[r][k], *(const float4*)&Aug[k][36 + c0], acc);
    return acc;
}

// ---------------- compose (256 threads, conflict-free) ---------------------
// result: E''->Msv, F''->T5, G''->T3. Destroys Ea (becomes Fa^T) and Gb
// (becomes Fb^T). Ends barrier'd.
__device__ void compose256(int tid,
    float (*Ea)[36], const float (*Fa)[36], const float (*Ga)[36],
    const float (*Eb)[36], const float (*Fb)[36], float (*Gb)[36],
    float (*Msv)[36], float (*T1)[36], float (*T3)[36], float (*T4)[36], float (*T5)[36],
    float (*Aug)[72])
{
    const int r = tid >> 3, c0 = (tid & 7) * 4;
    // M = I + Gb*Ea -> AugL, Msv ; AugR = I
    {
        float4 m4 = mm4(Gb, Ea, r, c0);
        m4.x += (r == c0 + 0) ? 1.f : 0.f; m4.y += (r == c0 + 1) ? 1.f : 0.f;
        m4.z += (r == c0 + 2) ? 1.f : 0.f; m4.w += (r == c0 + 3) ? 1.f : 0.f;
        float4 id4 = make_float4((r == c0 + 0) ? 1.f : 0.f, (r == c0 + 1) ? 1.f : 0.f,
                                 (r == c0 + 2) ? 1.f : 0.f, (r == c0 + 3) ? 1.f : 0.f);
        *(float4*)&Aug[r][c0] = m4;
        *(float4*)&Msv[r][c0] = m4;
        *(float4*)&Aug[r][36 + c0] = id4;
    }
    __syncthreads();
    inv32_256(tid, Aug, Msv, T4);             // K in AugL, K^T in AugR
    // A: T1 = Ea*K ; T4 = K*Gb ; T3 = Fb*K^T
    {
        float4 t1 = mm4K(Ea, Aug, r, c0);
        float4 t4 = mmK4(Aug, Gb, r, c0);
        float4 t3 = mm4R(Fb, Aug, r, c0);
        *(float4*)&T1[r][c0] = t1; *(float4*)&T4[r][c0] = t4; *(float4*)&T3[r][c0] = t3;
    }
    __syncthreads();
    // B: AugR = Fb*T1 ; T5 = T3*Fa ; Ea <- Fa^T ; Gb <- Fb^T
    {
        float4 bt = mm4(Fb, T1, r, c0);
        float4 t5 = mm4(T3, Fa, r, c0);
        float4 fav = *(const float4*)&Fa[r][c0];
        float4 fbv = *(const float4*)&Fb[r][c0];
        *(float4*)&Aug[r][36 + c0] = bt; *(float4*)&T5[r][c0] = t5;
        Ea[c0 + 0][r] = fav.x; Ea[c0 + 1][r] = fav.y;
        Ea[c0 + 2][r] = fav.z; Ea[c0 + 3][r] = fav.w;
        Gb[c0 + 0][r] = fbv.x; Gb[c0 + 1][r] = fbv.y;
        Gb[c0 + 2][r] = fbv.z; Gb[c0 + 3][r] = fbv.w;
    }
    __syncthreads();
    // C: Msv = Eb + AugR*Fb^T(Gb) ; T1 = Fa^T(Ea)*T4
    {
        float4 ev = *(const float4*)&Eb[r][c0];
        float4 acc = f4z();
#pragma unroll
        for (int k = 0; k < 32; ++k) acc = f4madd(Aug[r][36 + k], *(const float4*)&Gb[k][c0], acc);
        ev.x += acc.x; ev.y += acc.y; ev.z += acc.z; ev.w += acc.w;
        float4 t1n = mm4(Ea, T4, r, c0);
        *(float4*)&Msv[r][c0] = ev;
        *(float4*)&T1[r][c0] = t1n;
    }
    __syncthreads();
    // D: T3 = Ga + T1*Fa
    {
        float4 g4 = mm4(T1, Fa, r, c0);
        float4 ga = *(const float4*)&Ga[r][c0];
        g4.x += ga.x; g4.y += ga.y; g4.z += ga.z; g4.w += ga.w;
        *(float4*)&T3[r][c0] = g4;
    }
    __syncthreads();
}

__device__ __forceinline__ void load_el256(const float* g, int tid,
    float (*E)[36], float (*F)[36], float (*G)[36]) {
    const int r = tid >> 3, c0 = (tid & 7) * 4;
    *(float4*)&E[r][c0] = *(const float4*)&g[tid * 4];
    *(float4*)&F[r][c0] = *(const float4*)&g[1024 + tid * 4];
    *(float4*)&G[r][c0] = *(const float4*)&g[2048 + tid * 4];
}

#define COMPOSE_SHARED \
    __shared__ float Ea[32][36], Fa[32][36], Ga[32][36]; \
    __shared__ float Eb[32][36], Fb[32][36], Gb[32][36]; \
    __shared__ float Msv[32][36], T1[32][36], T3[32][36], T4[32][36], T5[32][36]; \
    __shared__ float Aug[32][72];

// ---------------------------------------------------------------------------
// INIT: base element {E=Q, F=F, G=H^T R^-1 H} -> X slot 0
// ---------------------------------------------------------------------------
__global__ __launch_bounds__(256) void kf_init(
    const float* __restrict__ F, const float* __restrict__ H,
    const float* __restrict__ Q, const float* __restrict__ R,
    float* __restrict__ out)
{
    __shared__ float Hs[8][36], RHs[8][36], Rl[8][12], Ri[8][12];
    const int tid = threadIdx.x, r = tid >> 3, c0 = (tid & 7) * 4;
    if (tid < 64) *(float4*)&Hs[tid >> 3][(tid & 7) * 4] = *(const float4*)&H[tid * 4];
    if (tid < 64) Rl[tid >> 3][tid & 7] = R[tid];
    __syncthreads();
    inv8_wave(tid, Rl, Ri);
    __syncthreads();
    {   // RH = R^-1 * H
        int m = tid >> 5, jj = tid & 31;
        float s = 0.f;
#pragma unroll
        for (int n = 0; n < 8; ++n) s += Ri[m][n] * Hs[n][jj];
        RHs[m][jj] = s;
    }
    __syncthreads();
    float* base = out + XT_OFF;
    {   // G = H^T * RH (4/thread)
        float4 acc = f4z();
#pragma unroll
        for (int m = 0; m < 8; ++m) acc = f4madd(Hs[m][r], *(const float4*)&RHs[m][c0], acc);
        *(float4*)&base[2048 + tid * 4] = acc;
    }
    *(float4*)&base[tid * 4]        = *(const float4*)&Q[tid * 4];
    *(float4*)&base[1024 + tid * 4] = *(const float4*)&F[tid * 4];
}

// ---------------------------------------------------------------------------
// LVL: one compose per block, task-driven (level-parallel power DAG)
// ---------------------------------------------------------------------------
__global__ __launch_bounds__(256) void kf_lvl(LvlTasks tk, float* __restrict__ out)
{
    COMPOSE_SHARED
    const int tid = threadIdx.x;
    const int4 T = tk.t[blockIdx.x];
    load_el256(slot_c(out, T.y), tid, Ea, Fa, Ga);
    load_el256(slot_c(out, T.z), tid, Eb, Fb, Gb);
    __syncthreads();
    compose256(tid, Ea, Fa, Ga, Eb, Fb, Gb, Msv, T1, T3, T4, T5, Aug);
    // store symmetrized {E'',F'',G''}
    const int r = tid >> 3, c0 = (tid & 7) * 4;
    float* pd = slot_w(out, T.x);
    float4 e, f, g;
    e.x = 0.5f * (Msv[r][c0 + 0] + Msv[c0 + 0][r]); e.y = 0.5f * (Msv[r][c0 + 1] + Msv[c0 + 1][r]);
    e.z = 0.5f * (Msv[r][c0 + 2] + Msv[c0 + 2][r]); e.w = 0.5f * (Msv[r][c0 + 3] + Msv[c0 + 3][r]);
    f = *(const float4*)&T5[r][c0];
    g.x = 0.5f * (T3[r][c0 + 0] + T3[c0 + 0][r]); g.y = 0.5f * (T3[r][c0 + 1] + T3[c0 + 1][r]);
    g.z = 0.5f * (T3[r][c0 + 2] + T3[c0 + 2][r]); g.w = 0.5f * (T3[r][c0 + 3] + T3[c0 + 3][r]);
    *(float4*)&pd[tid * 4] = e;
    *(float4*)&pd[1024 + tid * 4] = f;
    *(float4*)&pd[2048 + tid * 4] = g;
}

// ---------------------------------------------------------------------------
// FINAL: per t, prefix = X^s o Y^q (one compose), recover P_t, build tables
// ---------------------------------------------------------------------------
__global__ __launch_bounds__(256) void kf_final(
    const float* __restrict__ Fg, const float* __restrict__ Hg,
    const float* __restrict__ Rg, const float* __restrict__ P0,
    const float* __restrict__ outc, float* __restrict__ ws)
{
    COMPOSE_SHARED
    __shared__ float Hs[8][36], HPs[8][36], Wms[8][36], Ums[8][36];
    __shared__ float Ss[8][12], Rs[8][12], Sis[8][12];
    const int t = blockIdx.x, tid = threadIdx.x, r = tid >> 3, c0 = (tid & 7) * 4;

    if (t == 0) {
        *(float4*)&Eb[r][c0] = *(const float4*)&P0[tid * 4];
        __syncthreads();
    } else {
        const int i = t - 1, s = (i & 15) + 1, q = i >> 4;
        if (q == 0) {
            load_el256(outc + XT_OFF + (size_t)(s - 1) * EL, tid, Msv, T5, T3);
            __syncthreads();
        } else {
            const float* pb = (q == 1) ? (outc + XT_OFF + 15 * (size_t)EL)
                                       : (outc + YT_OFF + (size_t)(q - 2) * EL);
            load_el256(outc + XT_OFF + (size_t)(s - 1) * EL, tid, Ea, Fa, Ga);
            load_el256(pb, tid, Eb, Fb, Gb);
            __syncthreads();
            compose256(tid, Ea, Fa, Ga, Eb, Fb, Gb, Msv, T1, T3, T4, T5, Aug);
        }
        // P_t = E + F*(P0*(I+G*P0)^-1)*F^T    (E=Msv, F=T5, G=T3)
        *(float4*)&Ea[r][c0] = *(const float4*)&P0[tid * 4];
        __syncthreads();
        {
            float4 m4 = mm4(T3, Ea, r, c0);
            m4.x += (r == c0 + 0) ? 1.f : 0.f; m4.y += (r == c0 + 1) ? 1.f : 0.f;
            m4.z += (r == c0 + 2) ? 1.f : 0.f; m4.w += (r == c0 + 3) ? 1.f : 0.f;
            float4 id4 = make_float4((r == c0 + 0) ? 1.f : 0.f, (r == c0 + 1) ? 1.f : 0.f,
                                     (r == c0 + 2) ? 1.f : 0.f, (r == c0 + 3) ? 1.f : 0.f);
            *(float4*)&Aug[r][c0] = m4; *(float4*)&T4[r][c0] = m4;
            *(float4*)&Aug[r][36 + c0] = id4;
        }
        __syncthreads();
        inv32_256(tid, Aug, T4, T1);          // K in AugL
        *(float4*)&T1[r][c0] = mm4K(Ea, Aug, r, c0);      // P0*K
        __syncthreads();
        *(float4*)&T4[r][c0] = mm4(T5, T1, r, c0);        // F*(P0K)
        __syncthreads();
        {   // Fa-slot(temp in Eb later): Msv + T4*T5^T (symmetric up to fp)
            float4 ev = *(const float4*)&Msv[r][c0];
            float s0 = 0, s1 = 0, s2 = 0, s3 = 0;
#pragma unroll
            for (int k = 0; k < 32; ++k) {
                float av = T4[r][k];
                s0 += av * T5[c0 + 0][k]; s1 += av * T5[c0 + 1][k];
                s2 += av * T5[c0 + 2][k]; s3 += av * T5[c0 + 3][k];
            }
            ev.x += s0; ev.y += s1; ev.z += s2; ev.w += s3;
            *(float4*)&Ga[r][c0] = ev;
        }
        __syncthreads();
        {   // Pm symmetrized -> Eb
            float4 e;
            e.x = 0.5f * (Ga[r][c0 + 0] + Ga[c0 + 0][r]); e.y = 0.5f * (Ga[r][c0 + 1] + Ga[c0 + 1][r]);
            e.z = 0.5f * (Ga[r][c0 + 2] + Ga[c0 + 2][r]); e.w = 0.5f * (Ga[r][c0 + 3] + Ga[c0 + 3][r]);
            *(float4*)&Eb[r][c0] = e;
        }
        __syncthreads();
    }

    // ---- tables from Pm = Eb ----
    *(float4*)&Fa[r][c0] = *(const float4*)&Fg[tid * 4];
    if (tid < 64) *(float4*)&Hs[tid >> 3][(tid & 7) * 4] = *(const float4*)&Hg[tid * 4];
    if (tid < 64) Rs[tid >> 3][tid & 7] = Rg[tid];
    __syncthreads();
    {   // HP = H*Pm
        int m = tid >> 5, k2 = tid & 31;
        float a = 0.f;
#pragma unroll
        for (int j = 0; j < 32; ++j) a += Hs[m][j] * Eb[j][k2];
        HPs[m][k2] = a;
    }
    __syncthreads();
    {   // W = HP*F^T ; S = HP*H^T + R (tid<64)
        int m = tid >> 5, jj = tid & 31;
        float wv = 0.f;
#pragma unroll
        for (int k = 0; k < 32; ++k) wv += HPs[m][k] * Fa[jj][k];
        Wms[m][jj] = wv;
        if (tid < 64) {
            int mm = tid >> 3, n = tid & 7;
            float sv = Rs[mm][n];
#pragma unroll
            for (int k = 0; k < 32; ++k) sv += HPs[mm][k] * Hs[n][k];
            Ss[mm][n] = sv;
            ws[S_OFF + (size_t)t * 64 + tid] = sv;
        }
    }
    __syncthreads();
    inv8_wave(tid, Ss, Sis);
    __syncthreads();
    {   // U = Si*W ; B_tab[t][s][m] = U[m][s]
        int m = tid >> 5, s2 = tid & 31;
        float u = 0.f;
#pragma unroll
        for (int n = 0; n < 8; ++n) u += Sis[m][n] * Wms[n][s2];
        Ums[m][s2] = u;
        ws[B_OFF + (size_t)t * 256 + s2 * 8 + m] = u;
    }
    __syncthreads();
    {   // A = F - U^T*H
        float4 a4 = *(const float4*)&Fa[r][c0];
#pragma unroll
        for (int m = 0; m < 8; ++m) {
            float um = Ums[m][r];
            a4 = f4madd(-um, *(const float4*)&Hs[m][c0], a4);
        }
        ((float4*)(ws + A_OFF))[(size_t)t * 256 + tid] = a4;
    }
}

// ---------------------------------------------------------------------------
// TPRE: per chunk (8 blocks), 32 serial steps: HT_t = H*T_{t0->t}, PHI_c
// ---------------------------------------------------------------------------
__global__ __launch_bounds__(256) void kf_tpre(
    const float* __restrict__ Hg, const float* __restrict__ ws,
    float* __restrict__ out)
{
    __shared__ float Ta[32][36], Tb[32][36], As[32][36], Hs[8][36];
    const int cc = blockIdx.x, tid = threadIdx.x, r = tid >> 3, c0 = (tid & 7) * 4;
    const int t0 = CH * cc;
    float* HT = out + HT_OFF;
    float* PHI = out + PHI_OFF;
    const float4* A4 = (const float4*)(ws + A_OFF);

    {
        float4 id4 = make_float4((r == c0 + 0) ? 1.f : 0.f, (r == c0 + 1) ? 1.f : 0.f,
                                 (r == c0 + 2) ? 1.f : 0.f, (r == c0 + 3) ? 1.f : 0.f);
        *(float4*)&Ta[r][c0] = id4;
    }
    if (tid < 64) *(float4*)&Hs[tid >> 3][(tid & 7) * 4] = *(const float4*)&Hg[tid * 4];
    HT[(size_t)t0 * 256 + tid] = Hg[tid & 255];
    *(float4*)&As[r][c0] = A4[(size_t)t0 * 256 + tid];
    __syncthreads();

    float (*cur)[36] = Ta, (*nxt)[36] = Tb;
    for (int k = 1; k <= CH; ++k) {
        *(float4*)&nxt[r][c0] = mm4(As, cur, r, c0);
        __syncthreads();
        if (k < CH) {
            int m = tid >> 5, s2 = tid & 31;
            float h = 0.f;
#pragma unroll
            for (int j = 0; j < 32; ++j) h += Hs[m][j] * nxt[j][s2];
            HT[(size_t)(t0 + k) * 256 + tid] = h;
            *(float4*)&As[r][c0] = A4[(size_t)(t0 + k) * 256 + tid];
        } else {
            ((float4*)PHI)[(size_t)cc * 256 + tid] = *(const float4*)&nxt[r][c0];
        }
        __syncthreads();
        float (*tmp)[36] = cur; cur = nxt; nxt = tmp;
    }
}

// ---------------------------------------------------------------------------
// M1: one-wave blocks; A_t/B_t/H in registers, m in LDS; zero barriers.
// ---------------------------------------------------------------------------
__global__ __launch_bounds__(64) void kf_m1(
    const float* __restrict__ obs, const float* __restrict__ Hg,
    const float* __restrict__ ws, float* __restrict__ out)
{
    __shared__ float mc[8][36];
    __shared__ float us[8][12];
    const int lane = threadIdx.x;
    const int rA = lane >> 1, hA = lane & 1;
    const int rH = lane >> 3, cH = lane & 7;
    const int cc = blockIdx.x >> 8;
    const int gb = (blockIdx.x & 255) * 8;
    const int t0 = cc * CH;
    const float4* A4 = (const float4*)(ws + A_OFF);
    const float4* B4 = (const float4*)(ws + B_OFF);
    const float4* obs4 = (const float4*)obs;
    float* means = out;
    float* MEND = out + MEND_OFF;

    const float4 h4 = *(const float4*)&Hg[rH * 32 + cH * 4];

    {
        float* mf = &mc[0][0];
        for (int i = lane; i < 8 * 36; i += 64) mf[i] = 0.f;
    }

    float4 an0 = A4[(size_t)t0 * 256 + lane * 4 + 0];
    float4 an1 = A4[(size_t)t0 * 256 + lane * 4 + 1];
    float4 an2 = A4[(size_t)t0 * 256 + lane * 4 + 2];
    float4 an3 = A4[(size_t)t0 * 256 + lane * 4 + 3];
    float4 bn  = B4[(size_t)t0 * 64 + lane];
    float4 un = f4z();
    if (lane < 16) un = obs4[((size_t)(gb + (lane >> 1)) * 256 + t0) * 2 + (lane & 1)];

    for (int k = 0; k < CH; ++k) {
        const int t = t0 + k;
        const float4 a0 = an0, a1 = an1, a2 = an2, a3 = an3, bb = bn;
        if (lane < 16) *(float4*)&us[lane >> 1][(lane & 1) * 4] = un;
        if (k < CH - 1) {
            an0 = A4[(size_t)(t + 1) * 256 + lane * 4 + 0];
            an1 = A4[(size_t)(t + 1) * 256 + lane * 4 + 1];
            an2 = A4[(size_t)(t + 1) * 256 + lane * 4 + 2];
            an3 = A4[(size_t)(t + 1) * 256 + lane * 4 + 3];
            bn  = B4[(size_t)(t + 1) * 64 + lane];
            if (lane < 16) un = obs4[((size_t)(gb + (lane >> 1)) * 256 + t + 1) * 2 + (lane & 1)];
        }
#pragma unroll 1
        for (int gl = 0; gl < 8; ++gl) {
            float4 mh = *(const float4*)&mc[gl][cH * 4];
            float hp = dot4(h4, mh);
            hp += __shfl_xor(hp, 1);
            hp += __shfl_xor(hp, 2);
            hp += __shfl_xor(hp, 4);
            float4 m0v = *(const float4*)&mc[gl][hA * 16 + 0];
            float4 m1v = *(const float4*)&mc[gl][hA * 16 + 4];
            float4 m2v = *(const float4*)&mc[gl][hA * 16 + 8];
            float4 m3v = *(const float4*)&mc[gl][hA * 16 + 12];
            float d = dot4(a0, m0v) + dot4(a1, m1v) + dot4(a2, m2v) + dot4(a3, m3v);
            float4 u4 = *(const float4*)&us[gl][hA * 4];
            d += dot4(bb, u4);
            d += __shfl_xor(d, 1);
            if ((lane & 7) == 0) means[((size_t)(gb + gl) * 256 + t) * 8 + rH] = hp;
            if (hA == 0) mc[gl][rA] = d;
        }
    }
#pragma unroll 1
    for (int gl = 0; gl < 8; ++gl)
        if (hA == 0) MEND[((size_t)(gb + gl) * 8 + cc) * 32 + rA] = mc[gl][rA];
}

// ---------------------------------------------------------------------------
// M23: chunk-state prefix per g + means correction (covs handled by kf_covs)
// ---------------------------------------------------------------------------
__global__ __launch_bounds__(256) void kf_m23(
    const float* __restrict__ m0, const float* __restrict__ ws,
    float* __restrict__ out)
{
    __shared__ float mst[8][8][36];
    const int tid = threadIdx.x, gl = tid >> 5, s = tid & 31;
    const size_t g = (size_t)blockIdx.x * 8 + gl;
    const float* MEND = out + MEND_OFF;
    const float4* HT4 = (const float4*)(out + HT_OFF);
    const float4* PHI4 = (const float4*)(out + PHI_OFF);
    float* means = out;

    float msr = m0[g * 32 + s];
    for (int cc = 0; cc < C_N; ++cc) {
        mst[gl][cc][s] = msr;
        if (cc < C_N - 1) {
            float nv = MEND[(g * 8 + cc) * 32 + s];
#pragma unroll
            for (int q4 = 0; q4 < 8; ++q4) {
                float4 p = PHI4[cc * 256 + s * 8 + q4];
                nv += p.x * __shfl(msr, 4 * q4 + 0, 32) + p.y * __shfl(msr, 4 * q4 + 1, 32)
                    + p.z * __shfl(msr, 4 * q4 + 2, 32) + p.w * __shfl(msr, 4 * q4 + 3, 32);
            }
            msr = nv;
        }
    }
    __syncthreads();

    const int m = s & 7, tq = s >> 3;
    for (int cc = 0; cc < C_N; ++cc) {
        const float* mrow = &mst[gl][cc][0];
#pragma unroll
        for (int it = 0; it < 8; ++it) {
            int t = cc * CH + it * 4 + tq;
            float corr = 0.f;
#pragma unroll
            for (int q4 = 0; q4 < 8; ++q4) {
                float4 h = HT4[(size_t)t * 64 + m * 8 + q4];
                const float4 mm = *(const float4*)&mrow[4 * q4];
                corr += dot4(h, mm);
            }
            means[g * 2048 + (size_t)t * 8 + m] += corr;
        }
    }
}

// ---------------------------------------------------------------------------
// COVS: broadcast S_t table into the full covs output (pure write BW)
// ---------------------------------------------------------------------------
__global__ void kf_covs(const float* __restrict__ ws, float* __restrict__ out)
{
    const float4* S4 = (const float4*)(ws + S_OFF);
    float4* covs4 = (float4*)out + COVS4_BASE;
    const size_t n = (size_t)G_N * T_N * 16;
    size_t i = (size_t)blockIdx.x * blockDim.x + threadIdx.x;
    const size_t stride = (size_t)gridDim.x * blockDim.x;
    for (; i < n; i += stride) {
        int t = (int)((i >> 4) & 255);
        int e4 = (int)(i & 15);
        covs4[i] = S4[t * 16 + e4];
    }
}

extern "C" void kernel_launch(void* const* d_in, const int* in_sizes, int n_in,
                              void* d_out, int out_size, void* d_ws, size_t ws_size,
                              hipStream_t stream) {
    const float* obs = (const float*)d_in[0];
    const float* F   = (const float*)d_in[1];
    const float* H   = (const float*)d_in[2];
    const float* Q   = (const float*)d_in[3];
    const float* R   = (const float*)d_in[4];
    const float* m0  = (const float*)d_in[5];
    const float* P0  = (const float*)d_in[6];
    float* out = (float*)d_out;
    float* ws  = (float*)d_ws;

    // level-parallel power DAG (slot: 0..15 = X^1..X^16 ; 16.. = Y^2..Y^15)
    LvlTasks L[8] = {};
    L[0].t[0] = make_int4(1, 0, 0, 0);
    L[1].t[0] = make_int4(2, 0, 1, 0);  L[1].t[1] = make_int4(3, 1, 1, 0);
    L[2].t[0] = make_int4(4, 0, 3, 0);  L[2].t[1] = make_int4(5, 1, 3, 0);
    L[2].t[2] = make_int4(6, 2, 3, 0);  L[2].t[3] = make_int4(7, 3, 3, 0);
    for (int i = 0; i < 8; ++i) L[3].t[i] = make_int4(8 + i, i, 7, 0);
    L[4].t[0] = make_int4(16, 15, 15, 0);
    L[5].t[0] = make_int4(17, 15, 16, 0); L[5].t[1] = make_int4(18, 16, 16, 0);
    L[6].t[0] = make_int4(19, 15, 18, 0); L[6].t[1] = make_int4(20, 16, 18, 0);
    L[6].t[2] = make_int4(21, 17, 18, 0); L[6].t[3] = make_int4(22, 18, 18, 0);
    for (int i = 0; i < 7; ++i) L[7].t[i] = make_int4(23 + i, 15 + i, 22, 0);
    const int ng[8] = {1, 2, 4, 8, 1, 2, 4, 7};

    kf_init <<<1, 256, 0, stream>>>(F, H, Q, R, out);
    for (int l = 0; l < 8; ++l)
        kf_lvl<<<ng[l], 256, 0, stream>>>(L[l], out);
    kf_final<<<256,  256, 0, stream>>>(F, H, R, P0, out, ws);
    kf_tpre <<<8,    256, 0, stream>>>(H, ws, out);
    kf_m1   <<<2048, 64,  0, stream>>>(obs, H, ws, out);
    kf_m23  <<<256,  256, 0, stream>>>(m0, ws, out);
    kf_covs <<<8192, 256, 0, stream>>>(ws, out);
}

// Round 8
// 438.453 us; speedup vs baseline: 1.3468x; 1.0902x over previous
//
#include <hip/hip_runtime.h>

#define G_N 2048
#define T_N 256
#define C_N 8          // chunks
#define CH 32          // chunk length

// ws layout (floats)
#define A_OFF 0
#define B_OFF 262144
#define S_OFF 327680

// out-tail scratch (float offsets into d_out); out total = 37748736 floats
#define OUT_TOTAL  37748736ull
#define EL         3072
#define MST_OFF    36506624ull   // [2048][8][32] chunk-start states
#define MEND_OFF   37030912ull   // [2048][8][32] chunk-end local states
#define HT_OFF     37555200ull   // [256][8][32]
#define PHI_OFF    37620736ull   // [8][32][32]
#define XT_OFF     37653504ull   // X^s at slot s-1, s=1..16 (16*EL)
#define YT_OFF     37702656ull   // Y^q at slot q-2, q=2..15 (14*EL)
#define COVS4_BASE 1048576ull
#define TAIL4_SKIP 8078080ull    // (MST_OFF - 4194304)/4 : covs float4 bound

struct LvlTasks { int4 t[8]; };   // x=dst slot, y=srcA slot, z=srcB slot

// ---------------- float4 helpers ------------------------------------------
__device__ __forceinline__ float4 f4z() { return make_float4(0.f, 0.f, 0.f, 0.f); }
__device__ __forceinline__ float4 f4madd(float s, const float4 v, float4 a) {
    a.x += s * v.x; a.y += s * v.y; a.z += s * v.z; a.w += s * v.w; return a;
}
__device__ __forceinline__ float dot4(const float4 a, const float4 b) {
    return a.x * b.x + a.y * b.y + a.z * b.z + a.w * b.w;
}

// slot -> global pointer
__device__ __forceinline__ const float* slot_c(const float* out, int s) {
    return out + ((s < 16) ? (XT_OFF + (size_t)s * EL) : (YT_OFF + (size_t)(s - 16) * EL));
}
__device__ __forceinline__ float* slot_w(float* out, int s) {
    return out + ((s < 16) ? (XT_OFF + (size_t)s * EL) : (YT_OFF + (size_t)(s - 16) * EL));
}

// ---------------- 8x8 inverse on wave 0 (shuffle GJ, SPD) ------------------
__device__ __forceinline__ void inv8_wave(int tid, const float (*A8)[12], float (*O8)[12]) {
    if (tid < 64) {
        int r = tid >> 3, c = tid & 7;
        float a = A8[r][c];
        float b = (r == c) ? 1.f : 0.f;
#pragma unroll
        for (int j = 0; j < 8; ++j) {
            float ajj = __shfl(a, j * 8 + j, 64);
            float pv = 1.0f / ajj;
            if (r == j) { a *= pv; b *= pv; }
            float ajc = __shfl(a, j * 8 + c, 64);
            float bjc = __shfl(b, j * 8 + c, 64);
            float arj = __shfl(a, r * 8 + j, 64);
            if (r != j) { a -= arj * ajc; b -= arj * bjc; }
        }
        O8[r][c] = b;
    }
}

// ---------------- in-register unpivoted 4x4 inverse ------------------------
__device__ __forceinline__ void inv4x4(float P[4][4]) {
#pragma unroll
    for (int j = 0; j < 4; ++j) {
        float pv = 1.0f / P[j][j];
        P[j][j] = pv;
#pragma unroll
        for (int c = 0; c < 4; ++c) if (c != j) P[j][c] *= pv;
#pragma unroll
        for (int r = 0; r < 4; ++r) if (r != j) {
            float f = P[r][j];
#pragma unroll
            for (int c = 0; c < 4; ++c) if (c != j) P[r][c] -= f * P[j][c];
            P[r][j] = -f * pv;
        }
    }
}

// ---------------- 256-thread 32x32 inverse (4x4 pivots + NS) ---------------
// pre: AugL=M, AugR=I, M saved in Msv (barrier'd).
// post: K in AugL, K^T in AugR, barrier'd.
__device__ void inv32_256(int tid, float (*Aug)[72], const float (*Msv)[36], float (*Tmp)[36]) {
    const int r = tid >> 3, c0 = (tid & 7) * 4;
#pragma unroll 1
    for (int jb = 0; jb < 8; ++jb) {
        const int p = 4 * jb;
        float P[4][4];
#pragma unroll
        for (int i = 0; i < 4; ++i)
#pragma unroll
            for (int q = 0; q < 4; ++q) P[i][q] = Aug[p + i][p + q];
        float L[4];
#pragma unroll
        for (int q = 0; q < 4; ++q) L[q] = Aug[r][p + q];
        float4 xl = *(float4*)&Aug[r][c0];
        float4 xr = *(float4*)&Aug[r][36 + c0];
        float4 ql[4], qr[4];
#pragma unroll
        for (int q = 0; q < 4; ++q) {
            ql[q] = *(float4*)&Aug[p + q][c0];
            qr[q] = *(float4*)&Aug[p + q][36 + c0];
        }
        __syncthreads();
        inv4x4(P);
        float4 nl, nr;
        if (r >= p && r < p + 4) {
            int i = r - p;
            nl = f4madd(P[i][3], ql[3], f4madd(P[i][2], ql[2], f4madd(P[i][1], ql[1], f4madd(P[i][0], ql[0], f4z()))));
            nr = f4madd(P[i][3], qr[3], f4madd(P[i][2], qr[2], f4madd(P[i][1], qr[1], f4madd(P[i][0], qr[0], f4z()))));
        } else {
            float LP[4];
#pragma unroll
            for (int q = 0; q < 4; ++q)
                LP[q] = L[0] * P[0][q] + L[1] * P[1][q] + L[2] * P[2][q] + L[3] * P[3][q];
            nl = xl; nr = xr;
#pragma unroll
            for (int q = 0; q < 4; ++q) { nl = f4madd(-LP[q], ql[q], nl); nr = f4madd(-LP[q], qr[q], nr); }
        }
        *(float4*)&Aug[r][c0] = nl;
        *(float4*)&Aug[r][36 + c0] = nr;
        __syncthreads();
    }
    // Newton-Schulz: K = 2*Kg - Kg*(M*Kg)
    float4 acc = f4z();
#pragma unroll
    for (int k = 0; k < 32; ++k) acc = f4madd(Msv[r][k], *(const float4*)&Aug[k][36 + c0], acc);
    *(float4*)&Tmp[r][c0] = acc;
    __syncthreads();
    float4 k4 = *(const float4*)&Aug[r][36 + c0];
    float4 a2 = f4z();
#pragma unroll
    for (int k = 0; k < 32; ++k) a2 = f4madd(Aug[r][36 + k], *(const float4*)&Tmp[k][c0], a2);
    float4 kv = make_float4(2.f * k4.x - a2.x, 2.f * k4.y - a2.y, 2.f * k4.z - a2.z, 2.f * k4.w - a2.w);
    __syncthreads();                          // all AugR reads complete
    *(float4*)&Aug[r][c0] = kv;               // K
    Aug[c0 + 0][36 + r] = kv.x;               // K^T into AugR
    Aug[c0 + 1][36 + r] = kv.y;
    Aug[c0 + 2][36 + r] = kv.z;
    Aug[c0 + 3][36 + r] = kv.w;
    __syncthreads();
}

// ---------------- matmul fragments (row-broadcast, conflict-free) ----------
__device__ __forceinline__ float4 mm4(const float (*A)[36], const float (*B)[36], int r, int c0) {
    float4 acc = f4z();
#pragma unroll
    for (int k = 0; k < 32; ++k) acc = f4madd(A[r][k], *(const float4*)&B[k][c0], acc);
    return acc;
}
__device__ __forceinline__ float4 mm4K(const float (*A)[36], const float (*Aug)[72], int r, int c0) {
    float4 acc = f4z();                       // A * K (K = AugL)
#pragma unroll
    for (int k = 0; k < 32; ++k) acc = f4madd(A[r][k], *(const float4*)&Aug[k][c0], acc);
    return acc;
}
__device__ __forceinline__ float4 mmK4(const float (*Aug)[72], const float (*B)[36], int r, int c0) {
    float4 acc = f4z();                       // K * B
#pragma unroll
    for (int k = 0; k < 32; ++k) acc = f4madd(Aug[r][k], *(const float4*)&B[k][c0], acc);
    return acc;
}
__device__ __forceinline__ float4 mm4R(const float (*A)[36], const float (*Aug)[72], int r, int c0) {
    float4 acc = f4z();                       // A * (AugR) ; AugR holds K^T
#pragma unroll
    for (int k = 0; k < 32; ++k) acc = f4madd(A[r][k], *(const float4*)&Aug[k][36 + c0], acc);
    return acc;
}

// ---------------- compose (256 threads, conflict-free) ---------------------
// result: E''->Msv, F''->T5, G''->T3. Destroys Ea (becomes Fa^T) and Gb
// (becomes Fb^T). Ends barrier'd.
__device__ void compose256(int tid,
    float (*Ea)[36], const float (*Fa)[36], const float (*Ga)[36],
    const float (*Eb)[36], const float (*Fb)[36], float (*Gb)[36],
    float (*Msv)[36], float (*T1)[36], float (*T3)[36], float (*T4)[36], float (*T5)[36],
    float (*Aug)[72])
{
    const int r = tid >> 3, c0 = (tid & 7) * 4;
    // M = I + Gb*Ea -> AugL, Msv ; AugR = I
    {
        float4 m4 = mm4(Gb, Ea, r, c0);
        m4.x += (r == c0 + 0) ? 1.f : 0.f; m4.y += (r == c0 + 1) ? 1.f : 0.f;
        m4.z += (r == c0 + 2) ? 1.f : 0.f; m4.w += (r == c0 + 3) ? 1.f : 0.f;
        float4 id4 = make_float4((r == c0 + 0) ? 1.f : 0.f, (r == c0 + 1) ? 1.f : 0.f,
                                 (r == c0 + 2) ? 1.f : 0.f, (r == c0 + 3) ? 1.f : 0.f);
        *(float4*)&Aug[r][c0] = m4;
        *(float4*)&Msv[r][c0] = m4;
        *(float4*)&Aug[r][36 + c0] = id4;
    }
    __syncthreads();
    inv32_256(tid, Aug, Msv, T4);             // K in AugL, K^T in AugR
    // A: T1 = Ea*K ; T4 = K*Gb ; T3 = Fb*K^T
    {
        float4 t1 = mm4K(Ea, Aug, r, c0);
        float4 t4 = mmK4(Aug, Gb, r, c0);
        float4 t3 = mm4R(Fb, Aug, r, c0);
        *(float4*)&T1[r][c0] = t1; *(float4*)&T4[r][c0] = t4; *(float4*)&T3[r][c0] = t3;
    }
    __syncthreads();
    // B: AugR = Fb*T1 ; T5 = T3*Fa ; Ea <- Fa^T ; Gb <- Fb^T
    {
        float4 bt = mm4(Fb, T1, r, c0);
        float4 t5 = mm4(T3, Fa, r, c0);
        float4 fav = *(const float4*)&Fa[r][c0];
        float4 fbv = *(const float4*)&Fb[r][c0];
        *(float4*)&Aug[r][36 + c0] = bt; *(float4*)&T5[r][c0] = t5;
        Ea[c0 + 0][r] = fav.x; Ea[c0 + 1][r] = fav.y;
        Ea[c0 + 2][r] = fav.z; Ea[c0 + 3][r] = fav.w;
        Gb[c0 + 0][r] = fbv.x; Gb[c0 + 1][r] = fbv.y;
        Gb[c0 + 2][r] = fbv.z; Gb[c0 + 3][r] = fbv.w;
    }
    __syncthreads();
    // C: Msv = Eb + AugR*Fb^T(Gb) ; T1 = Fa^T(Ea)*T4
    {
        float4 ev = *(const float4*)&Eb[r][c0];
        float4 acc = f4z();
#pragma unroll
        for (int k = 0; k < 32; ++k) acc = f4madd(Aug[r][36 + k], *(const float4*)&Gb[k][c0], acc);
        ev.x += acc.x; ev.y += acc.y; ev.z += acc.z; ev.w += acc.w;
        float4 t1n = mm4(Ea, T4, r, c0);
        *(float4*)&Msv[r][c0] = ev;
        *(float4*)&T1[r][c0] = t1n;
    }
    __syncthreads();
    // D: T3 = Ga + T1*Fa
    {
        float4 g4 = mm4(T1, Fa, r, c0);
        float4 ga = *(const float4*)&Ga[r][c0];
        g4.x += ga.x; g4.y += ga.y; g4.z += ga.z; g4.w += ga.w;
        *(float4*)&T3[r][c0] = g4;
    }
    __syncthreads();
}

__device__ __forceinline__ void load_el256(const float* g, int tid,
    float (*E)[36], float (*F)[36], float (*G)[36]) {
    const int r = tid >> 3, c0 = (tid & 7) * 4;
    *(float4*)&E[r][c0] = *(const float4*)&g[tid * 4];
    *(float4*)&F[r][c0] = *(const float4*)&g[1024 + tid * 4];
    *(float4*)&G[r][c0] = *(const float4*)&g[2048 + tid * 4];
}

#define COMPOSE_SHARED \
    __shared__ float Ea[32][36], Fa[32][36], Ga[32][36]; \
    __shared__ float Eb[32][36], Fb[32][36], Gb[32][36]; \
    __shared__ float Msv[32][36], T1[32][36], T3[32][36], T4[32][36], T5[32][36]; \
    __shared__ float Aug[32][72];

// ---------------------------------------------------------------------------
// INIT: base element {E=Q, F=F, G=H^T R^-1 H} -> X slot 0
// ---------------------------------------------------------------------------
__global__ __launch_bounds__(256) void kf_init(
    const float* __restrict__ F, const float* __restrict__ H,
    const float* __restrict__ Q, const float* __restrict__ R,
    float* __restrict__ out)
{
    __shared__ float Hs[8][36], RHs[8][36], Rl[8][12], Ri[8][12];
    const int tid = threadIdx.x, r = tid >> 3, c0 = (tid & 7) * 4;
    if (tid < 64) *(float4*)&Hs[tid >> 3][(tid & 7) * 4] = *(const float4*)&H[tid * 4];
    if (tid < 64) Rl[tid >> 3][tid & 7] = R[tid];
    __syncthreads();
    inv8_wave(tid, Rl, Ri);
    __syncthreads();
    {   // RH = R^-1 * H
        int m = tid >> 5, jj = tid & 31;
        float s = 0.f;
#pragma unroll
        for (int n = 0; n < 8; ++n) s += Ri[m][n] * Hs[n][jj];
        RHs[m][jj] = s;
    }
    __syncthreads();
    float* base = out + XT_OFF;
    {   // G = H^T * RH (4/thread)
        float4 acc = f4z();
#pragma unroll
        for (int m = 0; m < 8; ++m) acc = f4madd(Hs[m][r], *(const float4*)&RHs[m][c0], acc);
        *(float4*)&base[2048 + tid * 4] = acc;
    }
    *(float4*)&base[tid * 4]        = *(const float4*)&Q[tid * 4];
    *(float4*)&base[1024 + tid * 4] = *(const float4*)&F[tid * 4];
}

// ---------------------------------------------------------------------------
// LVL: one compose per block, task-driven (level-parallel power DAG)
// ---------------------------------------------------------------------------
__global__ __launch_bounds__(256) void kf_lvl(LvlTasks tk, float* __restrict__ out)
{
    COMPOSE_SHARED
    const int tid = threadIdx.x;
    const int4 T = tk.t[blockIdx.x];
    load_el256(slot_c(out, T.y), tid, Ea, Fa, Ga);
    load_el256(slot_c(out, T.z), tid, Eb, Fb, Gb);
    __syncthreads();
    compose256(tid, Ea, Fa, Ga, Eb, Fb, Gb, Msv, T1, T3, T4, T5, Aug);
    // store symmetrized {E'',F'',G''}
    const int r = tid >> 3, c0 = (tid & 7) * 4;
    float* pd = slot_w(out, T.x);
    float4 e, f, g;
    e.x = 0.5f * (Msv[r][c0 + 0] + Msv[c0 + 0][r]); e.y = 0.5f * (Msv[r][c0 + 1] + Msv[c0 + 1][r]);
    e.z = 0.5f * (Msv[r][c0 + 2] + Msv[c0 + 2][r]); e.w = 0.5f * (Msv[r][c0 + 3] + Msv[c0 + 3][r]);
    f = *(const float4*)&T5[r][c0];
    g.x = 0.5f * (T3[r][c0 + 0] + T3[c0 + 0][r]); g.y = 0.5f * (T3[r][c0 + 1] + T3[c0 + 1][r]);
    g.z = 0.5f * (T3[r][c0 + 2] + T3[c0 + 2][r]); g.w = 0.5f * (T3[r][c0 + 3] + T3[c0 + 3][r]);
    *(float4*)&pd[tid * 4] = e;
    *(float4*)&pd[1024 + tid * 4] = f;
    *(float4*)&pd[2048 + tid * 4] = g;
}

// ---------------------------------------------------------------------------
// FINAL: per t, prefix = Y^q o X^s (one compose), recover P_t, build tables
// ---------------------------------------------------------------------------
__global__ __launch_bounds__(256) void kf_final(
    const float* __restrict__ Fg, const float* __restrict__ Hg,
    const float* __restrict__ Rg, const float* __restrict__ P0,
    const float* __restrict__ outc, float* __restrict__ ws)
{
    COMPOSE_SHARED
    __shared__ float Hs[8][36], HPs[8][36], Wms[8][36], Ums[8][36];
    __shared__ float Ss[8][12], Rs[8][12], Sis[8][12];
    const int t = blockIdx.x, tid = threadIdx.x, r = tid >> 3, c0 = (tid & 7) * 4;

    if (t == 0) {
        *(float4*)&Eb[r][c0] = *(const float4*)&P0[tid * 4];
        __syncthreads();
    } else {
        const int i = t - 1, s = (i & 15) + 1, q = i >> 4;
        if (q == 0) {
            load_el256(outc + XT_OFF + (size_t)(s - 1) * EL, tid, Msv, T5, T3);
            __syncthreads();
        } else {
            const float* pb = (q == 1) ? (outc + XT_OFF + 15 * (size_t)EL)
                                       : (outc + YT_OFF + (size_t)(q - 2) * EL);
            load_el256(outc + XT_OFF + (size_t)(s - 1) * EL, tid, Ea, Fa, Ga);
            load_el256(pb, tid, Eb, Fb, Gb);
            __syncthreads();
            compose256(tid, Ea, Fa, Ga, Eb, Fb, Gb, Msv, T1, T3, T4, T5, Aug);
        }
        // P_t = E + F*(P0*(I+G*P0)^-1)*F^T    (E=Msv, F=T5, G=T3)
        *(float4*)&Ea[r][c0] = *(const float4*)&P0[tid * 4];
        __syncthreads();
        {
            float4 m4 = mm4(T3, Ea, r, c0);
            m4.x += (r == c0 + 0) ? 1.f : 0.f; m4.y += (r == c0 + 1) ? 1.f : 0.f;
            m4.z += (r == c0 + 2) ? 1.f : 0.f; m4.w += (r == c0 + 3) ? 1.f : 0.f;
            float4 id4 = make_float4((r == c0 + 0) ? 1.f : 0.f, (r == c0 + 1) ? 1.f : 0.f,
                                     (r == c0 + 2) ? 1.f : 0.f, (r == c0 + 3) ? 1.f : 0.f);
            *(float4*)&Aug[r][c0] = m4; *(float4*)&T4[r][c0] = m4;
            *(float4*)&Aug[r][36 + c0] = id4;
        }
        __syncthreads();
        inv32_256(tid, Aug, T4, T1);          // K in AugL
        *(float4*)&T1[r][c0] = mm4K(Ea, Aug, r, c0);      // P0*K
        __syncthreads();
        *(float4*)&T4[r][c0] = mm4(T5, T1, r, c0);        // F*(P0K)
        __syncthreads();
        {   // Ga(temp) = Msv + T4*T5^T
            float4 ev = *(const float4*)&Msv[r][c0];
            float s0 = 0, s1 = 0, s2 = 0, s3 = 0;
#pragma unroll
            for (int k = 0; k < 32; ++k) {
                float av = T4[r][k];
                s0 += av * T5[c0 + 0][k]; s1 += av * T5[c0 + 1][k];
                s2 += av * T5[c0 + 2][k]; s3 += av * T5[c0 + 3][k];
            }
            ev.x += s0; ev.y += s1; ev.z += s2; ev.w += s3;
            *(float4*)&Ga[r][c0] = ev;
        }
        __syncthreads();
        {   // Pm symmetrized -> Eb
            float4 e;
            e.x = 0.5f * (Ga[r][c0 + 0] + Ga[c0 + 0][r]); e.y = 0.5f * (Ga[r][c0 + 1] + Ga[c0 + 1][r]);
            e.z = 0.5f * (Ga[r][c0 + 2] + Ga[c0 + 2][r]); e.w = 0.5f * (Ga[r][c0 + 3] + Ga[c0 + 3][r]);
            *(float4*)&Eb[r][c0] = e;
        }
        __syncthreads();
    }

    // ---- tables from Pm = Eb ----
    *(float4*)&Fa[r][c0] = *(const float4*)&Fg[tid * 4];
    if (tid < 64) *(float4*)&Hs[tid >> 3][(tid & 7) * 4] = *(const float4*)&Hg[tid * 4];
    if (tid < 64) Rs[tid >> 3][tid & 7] = Rg[tid];
    __syncthreads();
    {   // HP = H*Pm
        int m = tid >> 5, k2 = tid & 31;
        float a = 0.f;
#pragma unroll
        for (int j = 0; j < 32; ++j) a += Hs[m][j] * Eb[j][k2];
        HPs[m][k2] = a;
    }
    __syncthreads();
    {   // W = HP*F^T ; S = HP*H^T + R (tid<64)
        int m = tid >> 5, jj = tid & 31;
        float wv = 0.f;
#pragma unroll
        for (int k = 0; k < 32; ++k) wv += HPs[m][k] * Fa[jj][k];
        Wms[m][jj] = wv;
        if (tid < 64) {
            int mm = tid >> 3, n = tid & 7;
            float sv = Rs[mm][n];
#pragma unroll
            for (int k = 0; k < 32; ++k) sv += HPs[mm][k] * Hs[n][k];
            Ss[mm][n] = sv;
            ws[S_OFF + (size_t)t * 64 + tid] = sv;
        }
    }
    __syncthreads();
    inv8_wave(tid, Ss, Sis);
    __syncthreads();
    {   // U = Si*W ; B_tab[t][s][m] = U[m][s]
        int m = tid >> 5, s2 = tid & 31;
        float u = 0.f;
#pragma unroll
        for (int n = 0; n < 8; ++n) u += Sis[m][n] * Wms[n][s2];
        Ums[m][s2] = u;
        ws[B_OFF + (size_t)t * 256 + s2 * 8 + m] = u;
    }
    __syncthreads();
    {   // A = F - U^T*H
        float4 a4 = *(const float4*)&Fa[r][c0];
#pragma unroll
        for (int m = 0; m < 8; ++m) {
            float um = Ums[m][r];
            a4 = f4madd(-um, *(const float4*)&Hs[m][c0], a4);
        }
        ((float4*)(ws + A_OFF))[(size_t)t * 256 + tid] = a4;
    }
}

// ---------------------------------------------------------------------------
// TPRE: per chunk (8 blocks), 32 serial steps: HT_t = H*T_{t0->t}, PHI_c
// ---------------------------------------------------------------------------
__global__ __launch_bounds__(256) void kf_tpre(
    const float* __restrict__ Hg, const float* __restrict__ ws,
    float* __restrict__ out)
{
    __shared__ float Ta[32][36], Tb[32][36], As[32][36], Hs[8][36];
    const int cc = blockIdx.x, tid = threadIdx.x, r = tid >> 3, c0 = (tid & 7) * 4;
    const int t0 = CH * cc;
    float* HT = out + HT_OFF;
    float* PHI = out + PHI_OFF;
    const float4* A4 = (const float4*)(ws + A_OFF);

    {
        float4 id4 = make_float4((r == c0 + 0) ? 1.f : 0.f, (r == c0 + 1) ? 1.f : 0.f,
                                 (r == c0 + 2) ? 1.f : 0.f, (r == c0 + 3) ? 1.f : 0.f);
        *(float4*)&Ta[r][c0] = id4;
    }
    if (tid < 64) *(float4*)&Hs[tid >> 3][(tid & 7) * 4] = *(const float4*)&Hg[tid * 4];
    HT[(size_t)t0 * 256 + tid] = Hg[tid & 255];
    *(float4*)&As[r][c0] = A4[(size_t)t0 * 256 + tid];
    __syncthreads();

    float (*cur)[36] = Ta, (*nxt)[36] = Tb;
    for (int k = 1; k <= CH; ++k) {
        *(float4*)&nxt[r][c0] = mm4(As, cur, r, c0);
        __syncthreads();
        if (k < CH) {
            int m = tid >> 5, s2 = tid & 31;
            float h = 0.f;
#pragma unroll
            for (int j = 0; j < 32; ++j) h += Hs[m][j] * nxt[j][s2];
            HT[(size_t)(t0 + k) * 256 + tid] = h;
            *(float4*)&As[r][c0] = A4[(size_t)(t0 + k) * 256 + tid];
        } else {
            ((float4*)PHI)[(size_t)cc * 256 + tid] = *(const float4*)&nxt[r][c0];
        }
        __syncthreads();
        float (*tmp)[36] = cur; cur = nxt; nxt = tmp;
    }
}

// ---------------------------------------------------------------------------
// M1: one-wave blocks; A_t/B_t/H in registers, m in LDS; zero barriers.
// ---------------------------------------------------------------------------
__global__ __launch_bounds__(64) void kf_m1(
    const float* __restrict__ obs, const float* __restrict__ Hg,
    const float* __restrict__ ws, float* __restrict__ out)
{
    __shared__ float mc[8][36];
    __shared__ float us[8][12];
    const int lane = threadIdx.x;
    const int rA = lane >> 1, hA = lane & 1;
    const int rH = lane >> 3, cH = lane & 7;
    const int cc = blockIdx.x >> 8;
    const int gb = (blockIdx.x & 255) * 8;
    const int t0 = cc * CH;
    const float4* A4 = (const float4*)(ws + A_OFF);
    const float4* B4 = (const float4*)(ws + B_OFF);
    const float4* obs4 = (const float4*)obs;
    float* means = out;
    float* MEND = out + MEND_OFF;

    const float4 h4 = *(const float4*)&Hg[rH * 32 + cH * 4];

    {
        float* mf = &mc[0][0];
        for (int i = lane; i < 8 * 36; i += 64) mf[i] = 0.f;
    }

    float4 an0 = A4[(size_t)t0 * 256 + lane * 4 + 0];
    float4 an1 = A4[(size_t)t0 * 256 + lane * 4 + 1];
    float4 an2 = A4[(size_t)t0 * 256 + lane * 4 + 2];
    float4 an3 = A4[(size_t)t0 * 256 + lane * 4 + 3];
    float4 bn  = B4[(size_t)t0 * 64 + lane];
    float4 un = f4z();
    if (lane < 16) un = obs4[((size_t)(gb + (lane >> 1)) * 256 + t0) * 2 + (lane & 1)];

    for (int k = 0; k < CH; ++k) {
        const int t = t0 + k;
        const float4 a0 = an0, a1 = an1, a2 = an2, a3 = an3, bb = bn;
        if (lane < 16) *(float4*)&us[lane >> 1][(lane & 1) * 4] = un;
        if (k < CH - 1) {
            an0 = A4[(size_t)(t + 1) * 256 + lane * 4 + 0];
            an1 = A4[(size_t)(t + 1) * 256 + lane * 4 + 1];
            an2 = A4[(size_t)(t + 1) * 256 + lane * 4 + 2];
            an3 = A4[(size_t)(t + 1) * 256 + lane * 4 + 3];
            bn  = B4[(size_t)(t + 1) * 64 + lane];
            if (lane < 16) un = obs4[((size_t)(gb + (lane >> 1)) * 256 + t + 1) * 2 + (lane & 1)];
        }
#pragma unroll 1
        for (int gl = 0; gl < 8; ++gl) {
            float4 mh = *(const float4*)&mc[gl][cH * 4];
            float hp = dot4(h4, mh);
            hp += __shfl_xor(hp, 1);
            hp += __shfl_xor(hp, 2);
            hp += __shfl_xor(hp, 4);
            float4 m0v = *(const float4*)&mc[gl][hA * 16 + 0];
            float4 m1v = *(const float4*)&mc[gl][hA * 16 + 4];
            float4 m2v = *(const float4*)&mc[gl][hA * 16 + 8];
            float4 m3v = *(const float4*)&mc[gl][hA * 16 + 12];
            float d = dot4(a0, m0v) + dot4(a1, m1v) + dot4(a2, m2v) + dot4(a3, m3v);
            float4 u4 = *(const float4*)&us[gl][hA * 4];
            d += dot4(bb, u4);
            d += __shfl_xor(d, 1);
            if ((lane & 7) == 0) means[((size_t)(gb + gl) * 256 + t) * 8 + rH] = hp;
            if (hA == 0) mc[gl][rA] = d;
        }
    }
#pragma unroll 1
    for (int gl = 0; gl < 8; ++gl)
        if (hA == 0) MEND[((size_t)(gb + gl) * 8 + cc) * 32 + rA] = mc[gl][rA];
}

// ---------------------------------------------------------------------------
// M23A: chunk-state prefix per g -> MST  (serial over 8 chunks; small)
// ---------------------------------------------------------------------------
__global__ __launch_bounds__(256) void kf_m23a(
    const float* __restrict__ m0, float* __restrict__ out)
{
    const int tid = threadIdx.x, gl = tid >> 5, s = tid & 31;
    const size_t g = (size_t)blockIdx.x * 8 + gl;
    const float* MEND = out + MEND_OFF;
    const float4* PHI4 = (const float4*)(out + PHI_OFF);
    float* MST = out + MST_OFF;

    float msr = m0[g * 32 + s];
    for (int cc = 0; cc < C_N; ++cc) {
        MST[g * 256 + (size_t)cc * 32 + s] = msr;
        if (cc < C_N - 1) {
            float nv = MEND[(g * 8 + cc) * 32 + s];
#pragma unroll
            for (int q4 = 0; q4 < 8; ++q4) {
                float4 p = PHI4[cc * 256 + s * 8 + q4];
                nv += p.x * __shfl(msr, 4 * q4 + 0, 32) + p.y * __shfl(msr, 4 * q4 + 1, 32)
                    + p.z * __shfl(msr, 4 * q4 + 2, 32) + p.w * __shfl(msr, 4 * q4 + 3, 32);
            }
            msr = nv;
        }
    }
}

// ---------------------------------------------------------------------------
// M23B: one g per block — means correction (coalesced RMW) + covs memcpy
// ---------------------------------------------------------------------------
__global__ __launch_bounds__(256) void kf_m23b(
    const float* __restrict__ ws, float* __restrict__ out)
{
    __shared__ float mst[256];
    const int tid = threadIdx.x;
    const size_t g = blockIdx.x;
    const float4* HT4 = (const float4*)(out + HT_OFF);
    float* means = out;

    mst[tid] = (out + MST_OFF)[g * 256 + tid];
    __syncthreads();

    // means correction: 8 outputs/thread, coalesced
#pragma unroll
    for (int j = 0; j < 8; ++j) {
        const int idx = tid + 256 * j;            // = t*8 + m
        const int t = idx >> 3, m = idx & 7, cc = t >> 5;
        float corr = 0.f;
#pragma unroll
        for (int q4 = 0; q4 < 8; ++q4) {
            float4 h = HT4[(size_t)t * 64 + m * 8 + q4];
            float4 mm = *(const float4*)&mst[cc * 32 + 4 * q4];
            corr += dot4(h, mm);
        }
        means[g * 2048 + idx] += corr;
    }

    // covs: per-g 64KB memcpy of the S-table (skip scratch tail)
    const float4* S4 = (const float4*)(ws + S_OFF);   // 4096 float4
    float4* covs4 = (float4*)out + COVS4_BASE;
#pragma unroll
    for (int k = 0; k < 16; ++k) {
        const size_t i = (size_t)tid + 256 * k;
        const size_t rel = g * 4096 + i;
        if (rel < TAIL4_SKIP) covs4[rel] = S4[i];
    }
}

// ---------------------------------------------------------------------------
// CLEAN: fill the covs span that was used as scratch
// ---------------------------------------------------------------------------
__global__ void kf_clean(const float* __restrict__ ws, float* __restrict__ out)
{
    float4* out4 = (float4*)out;
    const float4* S4 = (const float4*)(ws + S_OFF);
    const size_t start = COVS4_BASE + TAIL4_SKIP;
    const size_t end = OUT_TOTAL / 4;
    size_t i = start + (size_t)blockIdx.x * blockDim.x + threadIdx.x;
    const size_t stride = (size_t)gridDim.x * blockDim.x;
    for (; i < end; i += stride) {
        size_t rel = i - COVS4_BASE;
        out4[i] = S4[rel & 4095];
    }
}

extern "C" void kernel_launch(void* const* d_in, const int* in_sizes, int n_in,
                              void* d_out, int out_size, void* d_ws, size_t ws_size,
                              hipStream_t stream) {
    const float* obs = (const float*)d_in[0];
    const float* F   = (const float*)d_in[1];
    const float* H   = (const float*)d_in[2];
    const float* Q   = (const float*)d_in[3];
    const float* R   = (const float*)d_in[4];
    const float* m0  = (const float*)d_in[5];
    const float* P0  = (const float*)d_in[6];
    float* out = (float*)d_out;
    float* ws  = (float*)d_ws;

    // level-parallel power DAG (slot: 0..15 = X^1..X^16 ; 16.. = Y^2..Y^15)
    LvlTasks L[8] = {};
    L[0].t[0] = make_int4(1, 0, 0, 0);
    L[1].t[0] = make_int4(2, 0, 1, 0);  L[1].t[1] = make_int4(3, 1, 1, 0);
    L[2].t[0] = make_int4(4, 0, 3, 0);  L[2].t[1] = make_int4(5, 1, 3, 0);
    L[2].t[2] = make_int4(6, 2, 3, 0);  L[2].t[3] = make_int4(7, 3, 3, 0);
    for (int i = 0; i < 8; ++i) L[3].t[i] = make_int4(8 + i, i, 7, 0);
    L[4].t[0] = make_int4(16, 15, 15, 0);
    L[5].t[0] = make_int4(17, 15, 16, 0); L[5].t[1] = make_int4(18, 16, 16, 0);
    L[6].t[0] = make_int4(19, 15, 18, 0); L[6].t[1] = make_int4(20, 16, 18, 0);
    L[6].t[2] = make_int4(21, 17, 18, 0); L[6].t[3] = make_int4(22, 18, 18, 0);
    for (int i = 0; i < 7; ++i) L[7].t[i] = make_int4(23 + i, 15 + i, 22, 0);
    const int ng[8] = {1, 2, 4, 8, 1, 2, 4, 7};

    kf_init <<<1, 256, 0, stream>>>(F, H, Q, R, out);
    for (int l = 0; l < 8; ++l)
        kf_lvl<<<ng[l], 256, 0, stream>>>(L[l], out);
    kf_final<<<256,  256, 0, stream>>>(F, H, R, P0, out, ws);
    kf_tpre <<<8,    256, 0, stream>>>(H, ws, out);
    kf_m1   <<<2048, 64,  0, stream>>>(obs, H, ws, out);
    kf_m23a <<<256,  256, 0, stream>>>(m0, out);
    kf_m23b <<<2048, 256, 0, stream>>>(ws, out);
    kf_clean<<<512,  256, 0, stream>>>(ws, out);
}